// Round 9
// baseline (229.356 us; speedup 1.0000x reference)
//
#include <hip/hip_runtime.h>
#include <math.h>

#define B_ 8
#define C_ 512
#define S_ 1024
#define HD 64
#define NHEADS 8
#define NGROUPS 8
#define DT_STEP 0.1f
#define EPS_GN 1e-5f

typedef __attribute__((ext_vector_type(8))) short bf16x8;
typedef __attribute__((ext_vector_type(4))) float f32x4;
typedef __attribute__((ext_vector_type(8))) unsigned short ushort8;
typedef __attribute__((ext_vector_type(4))) unsigned short ushort4_t;

static __device__ __forceinline__ unsigned short f2bf(float f) {
  unsigned int u = __builtin_bit_cast(unsigned int, f);
  u += 0x7fff + ((u >> 16) & 1);           // round-to-nearest-even
  return (unsigned short)(u >> 16);
}

static __device__ __forceinline__ float fast_tanh(float x) {
  float xc = fminf(fmaxf(x, -15.f), 15.f);
  float e = __expf(2.f * xc);
  return (e - 1.f) / (e + 1.f);
}

static __device__ __forceinline__ void load16_lds(const void* g, void* l) {
  __builtin_amdgcn_global_load_lds((const __attribute__((address_space(1))) void*)g,
                                   (__attribute__((address_space(3))) void*)l, 16, 0, 0);
}

// ---------------- prep: cast fp32 weights -> bf16  +  GroupNorm partial sums ----------------
// grid 1152: [0,640) cast work, [640,1152) gn_stats work
__global__ __launch_bounds__(256) void prep_kernel(
    const float* __restrict__ a, const float* __restrict__ b, const float* __restrict__ c,
    unsigned short* __restrict__ A, unsigned short* __restrict__ B, unsigned short* __restrict__ C,
    const float* __restrict__ x, float* __restrict__ gpart) {
  int bid = blockIdx.x;
  int tid = threadIdx.x;
  if (bid < 640) {
    const float* src; unsigned short* dst; int off;
    if (bid < 384) { src = a; dst = A; off = bid * 2048; }
    else if (bid < 512) { src = b; dst = B; off = (bid - 384) * 2048; }
    else { src = c; dst = C; off = (bid - 512) * 2048; }
    int i = off + tid * 8;
    f32x4 v0 = *(const f32x4*)(src + i);
    f32x4 v1 = *(const f32x4*)(src + i + 4);
    ushort8 o;
    o[0] = f2bf(v0[0]); o[1] = f2bf(v0[1]); o[2] = f2bf(v0[2]); o[3] = f2bf(v0[3]);
    o[4] = f2bf(v1[0]); o[5] = f2bf(v1[1]); o[6] = f2bf(v1[2]); o[7] = f2bf(v1[3]);
    *(ushort8*)(dst + i) = o;
    return;
  }
  int sbid = bid - 640;
  int bg = sbid >> 3, chunk = sbid & 7;
  const float* xp = x + (size_t)bg * 65536 + (size_t)chunk * 8192;
  float sum = 0.f, sq = 0.f;
  #pragma unroll
  for (int i = 0; i < 8; ++i) {
    f32x4 v = *(const f32x4*)(xp + i * 1024 + tid * 4);
    sum += v[0] + v[1] + v[2] + v[3];
    sq += v[0]*v[0] + v[1]*v[1] + v[2]*v[2] + v[3]*v[3];
  }
  #pragma unroll
  for (int off = 32; off >= 1; off >>= 1) {
    sum += __shfl_xor(sum, off, 64);
    sq  += __shfl_xor(sq, off, 64);
  }
  __shared__ float s1[4], s2[4];
  int wave = tid >> 6, lane = tid & 63;
  if (lane == 0) { s1[wave] = sum; s2[wave] = sq; }
  __syncthreads();
  if (tid == 0) {
    float S = s1[0] + s1[1] + s1[2] + s1[3];
    float Q = s2[0] + s2[1] + s2[2] + s2[3];
    gpart[bg * 16 + chunk * 2] = S;
    gpart[bg * 16 + chunk * 2 + 1] = Q;
  }
}

// ---------------- GroupNorm pass 2: normalize + transpose to h_t[B,S,C] bf16 ----------------
__global__ __launch_bounds__(256) void gn_apply_t(
    const float* __restrict__ x, const float* __restrict__ gpart,
    const float* __restrict__ scale, const float* __restrict__ bias,
    unsigned short* __restrict__ h_t) {
  int bid = blockIdx.x;
  int bg = bid >> 4, st = bid & 15;
  int b = bg >> 3, g = bg & 7;
  float S = 0.f, Q = 0.f;
  #pragma unroll
  for (int i = 0; i < 8; ++i) {
    S += gpart[bg * 16 + i * 2];
    Q += gpart[bg * 16 + i * 2 + 1];
  }
  float mean = S / 65536.f;
  float var = Q / 65536.f - mean * mean;
  float inv = rsqrtf(var + EPS_GN);

  int tid = threadIdx.x;
  int sl = tid >> 2;
  int cq = (tid & 3) * 16;
  float sA[16], sB[16];
  #pragma unroll
  for (int u = 0; u < 16; ++u) {
    float scv = scale[g * 64 + cq + u];
    sA[u] = inv * scv;
    sB[u] = bias[g * 64 + cq + u] - mean * inv * scv;
  }

  const float* xp = x + ((size_t)b * C_ + (size_t)g * 64) * S_;
  __shared__ float tile[64][65];
  #pragma unroll
  for (int it = 0; it < 16; ++it) {
    int lin = it * 256 + tid;
    int c = lin >> 6, s = lin & 63;
    tile[c][s] = xp[(size_t)c * S_ + st * 64 + s];
  }
  __syncthreads();
  unsigned short vals[16];
  #pragma unroll
  for (int u = 0; u < 16; ++u)
    vals[u] = f2bf(tile[cq + u][sl] * sA[u] + sB[u]);
  unsigned short* dst = h_t + ((size_t)b * S_ + st * 64 + sl) * C_ + g * 64 + cq;
  ushort8 lo, hi;
  #pragma unroll
  for (int u = 0; u < 8; ++u) { lo[u] = vals[u]; hi[u] = vals[u + 8]; }
  *(ushort8*)dst = lo;
  *(ushort8*)(dst + 8) = hi;
}

// ---------------- NT GEMM core: C[MB,NB] = A[MB,512] * B[NB,512]^T ----------------
template<int MB, int NB, int WMG, int WNG>
__device__ __forceinline__ void gemm_nt_core(
    const unsigned short* __restrict__ Ab,
    const unsigned short* __restrict__ Bb,
    unsigned short* ldsA, unsigned short* ldsB,
    f32x4* acc) {
  constexpr int TI = (MB / WMG) / 16;
  constexpr int TJ = (NB / WNG) / 16;
  constexpr int NQA = MB * 4 / 256;
  constexpr int NQB = NB * 4 / 256;
  const int K = 512;
  const int tid = threadIdx.x;
  const int w = tid >> 6, lane = tid & 63, quad = lane >> 4, l15 = lane & 15;
  const int wm = (WNG == 1) ? w : ((WMG == 1) ? 0 : (w >> 1));
  const int wn = (WNG == 1) ? 0 : ((WMG == 1) ? w : (w & 1));

  for (int k0 = 0; k0 < K; k0 += 32) {
    __syncthreads();
    #pragma unroll
    for (int q = 0; q < NQA; ++q) {
      int c = q * 256 + tid;
      load16_lds(Ab + (size_t)(c >> 2) * K + k0 + (c & 3) * 8, ldsA + c * 8);
    }
    #pragma unroll
    for (int q = 0; q < NQB; ++q) {
      int c = q * 256 + tid;
      load16_lds(Bb + (size_t)(c >> 2) * K + k0 + (c & 3) * 8, ldsB + c * 8);
    }
    __syncthreads();
    bf16x8 af[TI], bfr[TJ];
    #pragma unroll
    for (int i = 0; i < TI; ++i)
      af[i] = *(const bf16x8*)(ldsA + (wm * (MB / WMG) + i * 16 + l15) * 32 + quad * 8);
    #pragma unroll
    for (int j = 0; j < TJ; ++j)
      bfr[j] = *(const bf16x8*)(ldsB + (wn * (NB / WNG) + j * 16 + l15) * 32 + quad * 8);
    #pragma unroll
    for (int i = 0; i < TI; ++i)
      #pragma unroll
      for (int j = 0; j < TJ; ++j)
        acc[i * TJ + j] = __builtin_amdgcn_mfma_f32_16x16x32_bf16(af[i], bfr[j], acc[i * TJ + j], 0, 0, 0);
  }
}

// ---------------- QKV GEMM: W_bf[1536,512] x h_t[b][1024,512]^T ----------------
__global__ __launch_bounds__(256) void gemm_qkv_mfma(
    const unsigned short* __restrict__ Wbf, const unsigned short* __restrict__ h_t,
    const float* __restrict__ bias,
    unsigned short* __restrict__ Qt, unsigned short* __restrict__ Kt,
    unsigned short* __restrict__ Vt) {
  __shared__ __align__(16) unsigned short ldsA[128 * 32];
  __shared__ __align__(16) unsigned short ldsB[128 * 32];
  int b = blockIdx.z;
  int bm = blockIdx.y * 128, bn = blockIdx.x * 128;
  f32x4 acc[16];
  #pragma unroll
  for (int t = 0; t < 16; ++t) acc[t] = (f32x4){0.f, 0.f, 0.f, 0.f};
  gemm_nt_core<128, 128, 2, 2>(Wbf + (size_t)bm * 512,
                               h_t + ((size_t)b * S_ + bn) * 512, ldsA, ldsB, acc);
  int tid = threadIdx.x, w = tid >> 6, lane = tid & 63, quad = lane >> 4, l15 = lane & 15;
  int wm = w >> 1, wn = w & 1;
  int tensor = bm >> 9;
  float qscale = (tensor == 0) ? 0.125f : 1.0f;
  #pragma unroll
  for (int i = 0; i < 4; ++i) {
    #pragma unroll
    for (int j = 0; j < 4; ++j) {
      int m0 = bm + wm * 64 + i * 16 + quad * 4;
      int ng = bn + wn * 64 + j * 16 + l15;
      f32x4 v = acc[i * 4 + j];
      if (tensor < 2) {
        int head = (m0 >> 6) & 7, d0 = m0 & 63;
        ushort4_t pk;
        #pragma unroll
        for (int r = 0; r < 4; ++r) pk[r] = f2bf((v[r] + bias[m0 + r]) * qscale);
        unsigned short* dst = (tensor ? Kt : Qt) +
            (((size_t)(b * 8 + head) * S_ + ng) * 64 + d0);
        *(ushort4_t*)dst = pk;
      } else {
        #pragma unroll
        for (int r = 0; r < 4; ++r)
          Vt[(size_t)b * (C_ * S_) + (size_t)(m0 - 1024 + r) * S_ + ng] = f2bf(v[r] + bias[m0 + r]);
      }
    }
  }
}

// ---------------- Flash attention, bf16 MFMA, 2 q-groups per wave ----------------
// grid 512: bid = sblk*64 + (b*8+n); block covers 128 q-rows (wave: 32 rows = 2 groups)
__global__ __launch_bounds__(256) void attn_mfma(
    const unsigned short* __restrict__ Qt,   // [B][NH][S][HD] (pre-scaled)
    const unsigned short* __restrict__ Kt,
    const unsigned short* __restrict__ Vt,   // [B][C][S]
    float* __restrict__ hflat,               // [B][S][C] fp32
    unsigned short* __restrict__ hflat_bf) { // [B][S][C] bf16
  int tid = threadIdx.x, wave = tid >> 6, lane = tid & 63;
  int quad = lane >> 4, l15 = lane & 15;
  int bid = blockIdx.x;
  int bn = bid & 63, sblk = bid >> 6, b = bn >> 3, n = bn & 7;
  int s0w = sblk * 128 + wave * 32;

  __shared__ unsigned short k_lds[64][72];
  __shared__ unsigned short v_lds[64][72];
  __shared__ unsigned short p_lds[4][2][16][72];   // [wave][group][row][t]

  const unsigned short* Kb = Kt + ((size_t)(b * 8 + n)) * S_ * 64;
  const unsigned short* Vb = Vt + ((size_t)b * C_ + n * 64) * S_;

  bf16x8 qa[2][2];
  #pragma unroll
  for (int g = 0; g < 2; ++g) {
    const unsigned short* Qb = Qt + (((size_t)(b * 8 + n)) * S_ + s0w + g * 16 + l15) * 64;
    qa[g][0] = *(const bf16x8*)(Qb + quad * 8);
    qa[g][1] = *(const bf16x8*)(Qb + 32 + quad * 8);
  }

  bf16x8 ones;
  #pragma unroll
  for (int j = 0; j < 8; ++j) ones[j] = (short)0x3F80;

  f32x4 o_acc[2][4];
  f32x4 l_acc[2];
  #pragma unroll
  for (int g = 0; g < 2; ++g) {
    l_acc[g] = (f32x4){0.f, 0.f, 0.f, 0.f};
    #pragma unroll
    for (int dc = 0; dc < 4; ++dc) o_acc[g][dc] = (f32x4){0.f, 0.f, 0.f, 0.f};
  }

  for (int t0 = 0; t0 < S_; t0 += 64) {
    __syncthreads();
    #pragma unroll
    for (int it = 0; it < 2; ++it) {
      int idx = tid + it * 256;
      int row = idx >> 3, c8 = (idx & 7) * 8;
      *(ushort8*)&k_lds[row][c8] = *(const ushort8*)(Kb + (size_t)(t0 + row) * 64 + c8);
      *(ushort8*)&v_lds[row][c8] = *(const ushort8*)(Vb + (size_t)row * S_ + t0 + c8);
    }
    __syncthreads();

    // QK^T for both groups, sharing kb fragments
    f32x4 sc[2][4];
    #pragma unroll
    for (int tc = 0; tc < 4; ++tc) {
      bf16x8 kb0 = *(const bf16x8*)&k_lds[tc * 16 + l15][quad * 8];
      bf16x8 kb1 = *(const bf16x8*)&k_lds[tc * 16 + l15][32 + quad * 8];
      #pragma unroll
      for (int g = 0; g < 2; ++g) {
        f32x4 c = {0.f, 0.f, 0.f, 0.f};
        c = __builtin_amdgcn_mfma_f32_16x16x32_bf16(qa[g][0], kb0, c, 0, 0, 0);
        sc[g][tc] = __builtin_amdgcn_mfma_f32_16x16x32_bf16(qa[g][1], kb1, c, 0, 0, 0);
      }
    }

    // exp (no max subtraction; scores bounded) -> P to wave-local LDS
    #pragma unroll
    for (int g = 0; g < 2; ++g)
      #pragma unroll
      for (int tc = 0; tc < 4; ++tc)
        #pragma unroll
        for (int r = 0; r < 4; ++r)
          p_lds[wave][g][quad * 4 + r][tc * 16 + l15] = f2bf(__expf(sc[g][tc][r]));

    bf16x8 pa[2][2];
    #pragma unroll
    for (int g = 0; g < 2; ++g) {
      pa[g][0] = *(const bf16x8*)&p_lds[wave][g][l15][quad * 8];
      pa[g][1] = *(const bf16x8*)&p_lds[wave][g][l15][32 + quad * 8];
      l_acc[g] = __builtin_amdgcn_mfma_f32_16x16x32_bf16(pa[g][0], ones, l_acc[g], 0, 0, 0);
      l_acc[g] = __builtin_amdgcn_mfma_f32_16x16x32_bf16(pa[g][1], ones, l_acc[g], 0, 0, 0);
    }
    // PV, sharing vb fragments across groups
    #pragma unroll
    for (int dc = 0; dc < 4; ++dc) {
      bf16x8 vb0 = *(const bf16x8*)&v_lds[dc * 16 + l15][quad * 8];
      bf16x8 vb1 = *(const bf16x8*)&v_lds[dc * 16 + l15][32 + quad * 8];
      #pragma unroll
      for (int g = 0; g < 2; ++g) {
        o_acc[g][dc] = __builtin_amdgcn_mfma_f32_16x16x32_bf16(pa[g][0], vb0, o_acc[g][dc], 0, 0, 0);
        o_acc[g][dc] = __builtin_amdgcn_mfma_f32_16x16x32_bf16(pa[g][1], vb1, o_acc[g][dc], 0, 0, 0);
      }
    }
  }

  #pragma unroll
  for (int g = 0; g < 2; ++g) {
    float inv_l[4];
    #pragma unroll
    for (int r = 0; r < 4; ++r) inv_l[r] = 1.f / l_acc[g][r];
    #pragma unroll
    for (int dc = 0; dc < 4; ++dc) {
      #pragma unroll
      for (int r = 0; r < 4; ++r) {
        int s = s0w + g * 16 + quad * 4 + r;
        size_t idx = ((size_t)b * S_ + s) * C_ + n * 64 + dc * 16 + l15;
        float val = o_acc[g][dc][r] * inv_l[r];
        hflat[idx] = val;
        hflat_bf[idx] = f2bf(val);
      }
    }
  }
}

// ---------------- INL step (64x128 tile, 512 blocks = 2/CU) ----------------
__global__ __launch_bounds__(256) void inl_step_mfma(
    const unsigned short* __restrict__ hbf_in, const unsigned short* __restrict__ Wbf,
    const float* __restrict__ bias, const float* __restrict__ h32_in,
    float* __restrict__ h32_out, unsigned short* __restrict__ hbf_out) {
  __shared__ __align__(16) unsigned short ldsA[64 * 32];
  __shared__ __align__(16) unsigned short ldsB[128 * 32];
  int bm = blockIdx.y * 64, bn = blockIdx.x * 128;
  f32x4 acc[8];
  #pragma unroll
  for (int t = 0; t < 8; ++t) acc[t] = (f32x4){0.f, 0.f, 0.f, 0.f};
  gemm_nt_core<64, 128, 1, 4>(hbf_in + (size_t)bm * 512,
                              Wbf + (size_t)bn * 512, ldsA, ldsB, acc);
  int tid = threadIdx.x, w = tid >> 6, lane = tid & 63, quad = lane >> 4, l15 = lane & 15;
  #pragma unroll
  for (int i = 0; i < 4; ++i) {
    #pragma unroll
    for (int j = 0; j < 2; ++j) {
      int m0 = bm + i * 16 + quad * 4;
      int o = bn + w * 32 + j * 16 + l15;
      float bv = bias[o];
      f32x4 v = acc[i * 2 + j];
      #pragma unroll
      for (int r = 0; r < 4; ++r) {
        size_t idx = (size_t)(m0 + r) * 512 + o;
        float val = h32_in[idx] + DT_STEP * fast_tanh(v[r] + bv);
        h32_out[idx] = val;
        hbf_out[idx] = f2bf(val);
      }
    }
  }
}

// ---------------- Proj (64x128 tile, 512 blocks) + residual ----------------
__global__ __launch_bounds__(256) void gemm_proj_mfma(
    const unsigned short* __restrict__ Wbf, const unsigned short* __restrict__ hbf,
    const float* __restrict__ pb, const float* __restrict__ x,
    float* __restrict__ Out) {
  __shared__ __align__(16) unsigned short ldsA[64 * 32];
  __shared__ __align__(16) unsigned short ldsB[128 * 32];
  int bm = blockIdx.y * 64, bn = blockIdx.x * 128;
  f32x4 acc[8];
  #pragma unroll
  for (int t = 0; t < 8; ++t) acc[t] = (f32x4){0.f, 0.f, 0.f, 0.f};
  gemm_nt_core<64, 128, 1, 4>(Wbf + (size_t)bm * 512,
                              hbf + (size_t)bn * 512, ldsA, ldsB, acc);
  int tid = threadIdx.x, w = tid >> 6, lane = tid & 63, quad = lane >> 4, l15 = lane & 15;
  #pragma unroll
  for (int i = 0; i < 4; ++i) {
    #pragma unroll
    for (int j = 0; j < 2; ++j) {
      int o0 = bm + i * 16 + quad * 4;
      int ng = bn + w * 32 + j * 16 + l15;
      int b = ng >> 10, s = ng & 1023;
      f32x4 v = acc[i * 2 + j];
      #pragma unroll
      for (int r = 0; r < 4; ++r) {
        size_t idx = ((size_t)b * C_ + o0 + r) * S_ + s;
        Out[idx] = x[idx] + pb[o0 + r] + v[r];
      }
    }
  }
}

extern "C" void kernel_launch(void* const* d_in, const int* in_sizes, int n_in,
                              void* d_out, int out_size, void* d_ws, size_t ws_size,
                              hipStream_t stream) {
  const float* x        = (const float*)d_in[0];
  const float* gn_scale = (const float*)d_in[1];
  const float* gn_bias  = (const float*)d_in[2];
  const float* qkv_w    = (const float*)d_in[3];
  const float* qkv_b    = (const float*)d_in[4];
  const float* proj_w   = (const float*)d_in[5];
  const float* proj_b   = (const float*)d_in[6];
  const float* inl_w    = (const float*)d_in[7];
  const float* inl_b    = (const float*)d_in[8];
  float* out = (float*)d_out;
  float* ws = (float*)d_ws;

  float* A32 = ws;
  float* B32 = ws + 4194304;
  unsigned short* Qt  = (unsigned short*)(ws + 8388608);
  unsigned short* Kt  = (unsigned short*)(ws + 10485760);
  unsigned short* Vt  = (unsigned short*)(ws + 12582912);
  unsigned short* h_t = (unsigned short*)(ws + 14680064);
  unsigned short* Bbf = h_t;
  unsigned short* Abf = (unsigned short*)(ws + 16777216);
  float* gpart = ws + 18874368;
  unsigned short* qkvw_bf  = (unsigned short*)(ws + 18878464);
  unsigned short* inlw_bf  = qkvw_bf + 786432;
  unsigned short* projw_bf = inlw_bf + 262144;

  prep_kernel<<<1152, 256, 0, stream>>>(qkv_w, inl_w, proj_w, qkvw_bf, inlw_bf, projw_bf, x, gpart);
  gn_apply_t<<<1024, 256, 0, stream>>>(x, gpart, gn_scale, gn_bias, h_t);
  gemm_qkv_mfma<<<dim3(8, 12, 8), 256, 0, stream>>>(qkvw_bf, h_t, qkv_b, Qt, Kt, Vt);
  attn_mfma<<<512, 256, 0, stream>>>(Qt, Kt, Vt, A32, Abf);
  inl_step_mfma<<<dim3(4, 128), 256, 0, stream>>>(Abf, inlw_bf, inl_b, A32, B32, Bbf);
  inl_step_mfma<<<dim3(4, 128), 256, 0, stream>>>(Bbf, inlw_bf, inl_b, B32, A32, Abf);
  inl_step_mfma<<<dim3(4, 128), 256, 0, stream>>>(Abf, inlw_bf, inl_b, A32, B32, Bbf);
  gemm_proj_mfma<<<dim3(64, 8), 256, 0, stream>>>(projw_bf, Bbf, proj_b, x, out);
}

// Round 10
// 218.160 us; speedup vs baseline: 1.0513x; 1.0513x over previous
//
#include <hip/hip_runtime.h>
#include <math.h>

#define B_ 8
#define C_ 512
#define S_ 1024
#define HD 64
#define NHEADS 8
#define NGROUPS 8
#define DT_STEP 0.1f
#define EPS_GN 1e-5f
#define LOG2E 1.4426950408889634f

typedef __attribute__((ext_vector_type(8))) short bf16x8;
typedef __attribute__((ext_vector_type(4))) float f32x4;
typedef __attribute__((ext_vector_type(8))) unsigned short ushort8;
typedef __attribute__((ext_vector_type(4))) unsigned short ushort4_t;

static __device__ __forceinline__ unsigned short f2bf(float f) {     // RNE (cold paths)
  unsigned int u = __builtin_bit_cast(unsigned int, f);
  u += 0x7fff + ((u >> 16) & 1);
  return (unsigned short)(u >> 16);
}

static __device__ __forceinline__ unsigned short f2bf_fast(float f) { // round-half-up (hot paths)
  unsigned int u = __builtin_bit_cast(unsigned int, f);
  return (unsigned short)((u + 0x8000u) >> 16);
}

static __device__ __forceinline__ float bf2f(unsigned short u) {
  unsigned int t = ((unsigned int)u) << 16;
  return __builtin_bit_cast(float, t);
}

static __device__ __forceinline__ float fast_tanh(float x) {
  float xc = fminf(fmaxf(x, -15.f), 15.f);
  float e = exp2f(xc * (2.0f * LOG2E));
  return (e - 1.f) / (e + 1.f);
}

static __device__ __forceinline__ void load16_lds(const void* g, void* l) {
  __builtin_amdgcn_global_load_lds((const __attribute__((address_space(1))) void*)g,
                                   (__attribute__((address_space(3))) void*)l, 16, 0, 0);
}

// ---------------- prep: cast fp32 weights -> bf16  +  GroupNorm partial sums ----------------
__global__ __launch_bounds__(256) void prep_kernel(
    const float* __restrict__ a, const float* __restrict__ b, const float* __restrict__ c,
    unsigned short* __restrict__ A, unsigned short* __restrict__ B, unsigned short* __restrict__ C,
    const float* __restrict__ x, float* __restrict__ gpart) {
  int bid = blockIdx.x;
  int tid = threadIdx.x;
  if (bid < 640) {
    const float* src; unsigned short* dst; int off;
    if (bid < 384) { src = a; dst = A; off = bid * 2048; }
    else if (bid < 512) { src = b; dst = B; off = (bid - 384) * 2048; }
    else { src = c; dst = C; off = (bid - 512) * 2048; }
    int i = off + tid * 8;
    f32x4 v0 = *(const f32x4*)(src + i);
    f32x4 v1 = *(const f32x4*)(src + i + 4);
    ushort8 o;
    o[0] = f2bf(v0[0]); o[1] = f2bf(v0[1]); o[2] = f2bf(v0[2]); o[3] = f2bf(v0[3]);
    o[4] = f2bf(v1[0]); o[5] = f2bf(v1[1]); o[6] = f2bf(v1[2]); o[7] = f2bf(v1[3]);
    *(ushort8*)(dst + i) = o;
    return;
  }
  int sbid = bid - 640;
  int bg = sbid >> 3, chunk = sbid & 7;
  const float* xp = x + (size_t)bg * 65536 + (size_t)chunk * 8192;
  float sum = 0.f, sq = 0.f;
  #pragma unroll
  for (int i = 0; i < 8; ++i) {
    f32x4 v = *(const f32x4*)(xp + i * 1024 + tid * 4);
    sum += v[0] + v[1] + v[2] + v[3];
    sq += v[0]*v[0] + v[1]*v[1] + v[2]*v[2] + v[3]*v[3];
  }
  #pragma unroll
  for (int off = 32; off >= 1; off >>= 1) {
    sum += __shfl_xor(sum, off, 64);
    sq  += __shfl_xor(sq, off, 64);
  }
  __shared__ float s1[4], s2[4];
  int wave = tid >> 6, lane = tid & 63;
  if (lane == 0) { s1[wave] = sum; s2[wave] = sq; }
  __syncthreads();
  if (tid == 0) {
    float S = s1[0] + s1[1] + s1[2] + s1[3];
    float Q = s2[0] + s2[1] + s2[2] + s2[3];
    gpart[bg * 16 + chunk * 2] = S;
    gpart[bg * 16 + chunk * 2 + 1] = Q;
  }
}

// ---------------- GroupNorm pass 2: normalize + transpose to h_t[B,S,C] bf16 ----------------
__global__ __launch_bounds__(256) void gn_apply_t(
    const float* __restrict__ x, const float* __restrict__ gpart,
    const float* __restrict__ scale, const float* __restrict__ bias,
    unsigned short* __restrict__ h_t) {
  int bid = blockIdx.x;
  int bg = bid >> 4, st = bid & 15;
  int b = bg >> 3, g = bg & 7;
  float S = 0.f, Q = 0.f;
  #pragma unroll
  for (int i = 0; i < 8; ++i) {
    S += gpart[bg * 16 + i * 2];
    Q += gpart[bg * 16 + i * 2 + 1];
  }
  float mean = S / 65536.f;
  float var = Q / 65536.f - mean * mean;
  float inv = rsqrtf(var + EPS_GN);

  int tid = threadIdx.x;
  int sl = tid >> 2;
  int cq = (tid & 3) * 16;
  float sA[16], sB[16];
  #pragma unroll
  for (int u = 0; u < 16; ++u) {
    float scv = scale[g * 64 + cq + u];
    sA[u] = inv * scv;
    sB[u] = bias[g * 64 + cq + u] - mean * inv * scv;
  }

  const float* xp = x + ((size_t)b * C_ + (size_t)g * 64) * S_;
  __shared__ float tile[64][65];
  #pragma unroll
  for (int it = 0; it < 16; ++it) {
    int lin = it * 256 + tid;
    int c = lin >> 6, s = lin & 63;
    tile[c][s] = xp[(size_t)c * S_ + st * 64 + s];
  }
  __syncthreads();
  unsigned short vals[16];
  #pragma unroll
  for (int u = 0; u < 16; ++u)
    vals[u] = f2bf_fast(tile[cq + u][sl] * sA[u] + sB[u]);
  unsigned short* dst = h_t + ((size_t)b * S_ + st * 64 + sl) * C_ + g * 64 + cq;
  ushort8 lo, hi;
  #pragma unroll
  for (int u = 0; u < 8; ++u) { lo[u] = vals[u]; hi[u] = vals[u + 8]; }
  *(ushort8*)dst = lo;
  *(ushort8*)(dst + 8) = hi;
}

// ---------------- NT GEMM core: C[MB,NB] = A[MB,512] * B[NB,512]^T ----------------
template<int MB, int NB, int WMG, int WNG>
__device__ __forceinline__ void gemm_nt_core(
    const unsigned short* __restrict__ Ab,
    const unsigned short* __restrict__ Bb,
    unsigned short* ldsA, unsigned short* ldsB,
    f32x4* acc) {
  constexpr int TI = (MB / WMG) / 16;
  constexpr int TJ = (NB / WNG) / 16;
  constexpr int NQA = MB * 4 / 256;
  constexpr int NQB = NB * 4 / 256;
  const int K = 512;
  const int tid = threadIdx.x;
  const int w = tid >> 6, lane = tid & 63, quad = lane >> 4, l15 = lane & 15;
  const int wm = (WNG == 1) ? w : ((WMG == 1) ? 0 : (w >> 1));
  const int wn = (WNG == 1) ? 0 : ((WMG == 1) ? w : (w & 1));

  for (int k0 = 0; k0 < K; k0 += 32) {
    __syncthreads();
    #pragma unroll
    for (int q = 0; q < NQA; ++q) {
      int c = q * 256 + tid;
      load16_lds(Ab + (size_t)(c >> 2) * K + k0 + (c & 3) * 8, ldsA + c * 8);
    }
    #pragma unroll
    for (int q = 0; q < NQB; ++q) {
      int c = q * 256 + tid;
      load16_lds(Bb + (size_t)(c >> 2) * K + k0 + (c & 3) * 8, ldsB + c * 8);
    }
    __syncthreads();
    bf16x8 af[TI], bfr[TJ];
    #pragma unroll
    for (int i = 0; i < TI; ++i)
      af[i] = *(const bf16x8*)(ldsA + (wm * (MB / WMG) + i * 16 + l15) * 32 + quad * 8);
    #pragma unroll
    for (int j = 0; j < TJ; ++j)
      bfr[j] = *(const bf16x8*)(ldsB + (wn * (NB / WNG) + j * 16 + l15) * 32 + quad * 8);
    #pragma unroll
    for (int i = 0; i < TI; ++i)
      #pragma unroll
      for (int j = 0; j < TJ; ++j)
        acc[i * TJ + j] = __builtin_amdgcn_mfma_f32_16x16x32_bf16(af[i], bfr[j], acc[i * TJ + j], 0, 0, 0);
  }
}

// ---------------- QKV GEMM: W_bf[1536,512] x h_t[b][1024,512]^T ----------------
// Q pre-scaled by hd^-0.5 * log2(e) so attention uses exp2 directly.
__global__ __launch_bounds__(256) void gemm_qkv_mfma(
    const unsigned short* __restrict__ Wbf, const unsigned short* __restrict__ h_t,
    const float* __restrict__ bias,
    unsigned short* __restrict__ Qt, unsigned short* __restrict__ Kt,
    unsigned short* __restrict__ Vt) {
  __shared__ __align__(16) unsigned short ldsA[128 * 32];
  __shared__ __align__(16) unsigned short ldsB[128 * 32];
  int b = blockIdx.z;
  int bm = blockIdx.y * 128, bn = blockIdx.x * 128;
  f32x4 acc[16];
  #pragma unroll
  for (int t = 0; t < 16; ++t) acc[t] = (f32x4){0.f, 0.f, 0.f, 0.f};
  gemm_nt_core<128, 128, 2, 2>(Wbf + (size_t)bm * 512,
                               h_t + ((size_t)b * S_ + bn) * 512, ldsA, ldsB, acc);
  int tid = threadIdx.x, w = tid >> 6, lane = tid & 63, quad = lane >> 4, l15 = lane & 15;
  int wm = w >> 1, wn = w & 1;
  int tensor = bm >> 9;
  float qscale = (tensor == 0) ? 0.125f * LOG2E : 1.0f;
  #pragma unroll
  for (int i = 0; i < 4; ++i) {
    #pragma unroll
    for (int j = 0; j < 4; ++j) {
      int m0 = bm + wm * 64 + i * 16 + quad * 4;
      int ng = bn + wn * 64 + j * 16 + l15;
      f32x4 v = acc[i * 4 + j];
      if (tensor < 2) {
        int head = (m0 >> 6) & 7, d0 = m0 & 63;
        ushort4_t pk;
        #pragma unroll
        for (int r = 0; r < 4; ++r) pk[r] = f2bf((v[r] + bias[m0 + r]) * qscale);
        unsigned short* dst = (tensor ? Kt : Qt) +
            (((size_t)(b * 8 + head) * S_ + ng) * 64 + d0);
        *(ushort4_t*)dst = pk;
      } else {
        #pragma unroll
        for (int r = 0; r < 4; ++r)
          Vt[(size_t)b * (C_ * S_) + (size_t)(m0 - 1024 + r) * S_ + ng] = f2bf(v[r] + bias[m0 + r]);
      }
    }
  }
}

// ---------------- Flash attention, bf16 MFMA, no-max base-2 softmax ----------------
// grid 1024: bid = sblk*64 + (b*8+n); 4 waves x 16 q-rows (R8-proven shape)
__global__ __launch_bounds__(256) void attn_mfma(
    const unsigned short* __restrict__ Qt,   // [B][NH][S][HD] (pre-scaled, incl log2e)
    const unsigned short* __restrict__ Kt,
    const unsigned short* __restrict__ Vt,   // [B][C][S]
    unsigned short* __restrict__ hflat_bf) { // [B][S][C] bf16
  int tid = threadIdx.x, wave = tid >> 6, lane = tid & 63;
  int quad = lane >> 4, l15 = lane & 15;
  int bid = blockIdx.x;
  int bn = bid & 63, sblk = bid >> 6, b = bn >> 3, n = bn & 7;
  int s0w = sblk * 64 + wave * 16;

  __shared__ unsigned short k_lds[64][72];
  __shared__ unsigned short v_lds[64][72];
  __shared__ unsigned short p_lds[4][16][72];

  const unsigned short* Qb = Qt + (((size_t)(b * 8 + n)) * S_ + s0w + l15) * 64;
  const unsigned short* Kb = Kt + ((size_t)(b * 8 + n)) * S_ * 64;
  const unsigned short* Vb = Vt + ((size_t)b * C_ + n * 64) * S_;

  bf16x8 qa0 = *(const bf16x8*)(Qb + quad * 8);
  bf16x8 qa1 = *(const bf16x8*)(Qb + 32 + quad * 8);

  bf16x8 ones;
  #pragma unroll
  for (int j = 0; j < 8; ++j) ones[j] = (short)0x3F80;

  f32x4 o_acc[4];
  f32x4 l_acc = {0.f, 0.f, 0.f, 0.f};
  #pragma unroll
  for (int dc = 0; dc < 4; ++dc) o_acc[dc] = (f32x4){0.f, 0.f, 0.f, 0.f};

  for (int t0 = 0; t0 < S_; t0 += 64) {
    __syncthreads();
    #pragma unroll
    for (int it = 0; it < 2; ++it) {
      int idx = tid + it * 256;
      int row = idx >> 3, c8 = (idx & 7) * 8;
      *(ushort8*)&k_lds[row][c8] = *(const ushort8*)(Kb + (size_t)(t0 + row) * 64 + c8);
      *(ushort8*)&v_lds[row][c8] = *(const ushort8*)(Vb + (size_t)row * S_ + t0 + c8);
    }
    __syncthreads();

    f32x4 sc[4];
    #pragma unroll
    for (int tc = 0; tc < 4; ++tc) {
      bf16x8 kb0 = *(const bf16x8*)&k_lds[tc * 16 + l15][quad * 8];
      bf16x8 kb1 = *(const bf16x8*)&k_lds[tc * 16 + l15][32 + quad * 8];
      f32x4 c = {0.f, 0.f, 0.f, 0.f};
      c = __builtin_amdgcn_mfma_f32_16x16x32_bf16(qa0, kb0, c, 0, 0, 0);
      sc[tc] = __builtin_amdgcn_mfma_f32_16x16x32_bf16(qa1, kb1, c, 0, 0, 0);
    }

    // P = 2^score (Q carries 1/sqrt(hd)*log2e; scores bounded, fp32-safe)
    #pragma unroll
    for (int tc = 0; tc < 4; ++tc)
      #pragma unroll
      for (int r = 0; r < 4; ++r)
        p_lds[wave][quad * 4 + r][tc * 16 + l15] = f2bf_fast(exp2f(sc[tc][r]));

    bf16x8 pa0 = *(const bf16x8*)&p_lds[wave][l15][quad * 8];
    bf16x8 pa1 = *(const bf16x8*)&p_lds[wave][l15][32 + quad * 8];
    l_acc = __builtin_amdgcn_mfma_f32_16x16x32_bf16(pa0, ones, l_acc, 0, 0, 0);
    l_acc = __builtin_amdgcn_mfma_f32_16x16x32_bf16(pa1, ones, l_acc, 0, 0, 0);
    #pragma unroll
    for (int dc = 0; dc < 4; ++dc) {
      bf16x8 vb0 = *(const bf16x8*)&v_lds[dc * 16 + l15][quad * 8];
      bf16x8 vb1 = *(const bf16x8*)&v_lds[dc * 16 + l15][32 + quad * 8];
      o_acc[dc] = __builtin_amdgcn_mfma_f32_16x16x32_bf16(pa0, vb0, o_acc[dc], 0, 0, 0);
      o_acc[dc] = __builtin_amdgcn_mfma_f32_16x16x32_bf16(pa1, vb1, o_acc[dc], 0, 0, 0);
    }
  }

  float inv_l[4];
  #pragma unroll
  for (int r = 0; r < 4; ++r) inv_l[r] = 1.f / l_acc[r];
  #pragma unroll
  for (int dc = 0; dc < 4; ++dc) {
    #pragma unroll
    for (int r = 0; r < 4; ++r) {
      int s = s0w + quad * 4 + r;
      size_t idx = ((size_t)b * S_ + s) * C_ + n * 64 + dc * 16 + l15;
      hflat_bf[idx] = f2bf_fast(o_acc[dc][r] * inv_l[r]);
    }
  }
}

// ---------------- INL step (64x128 tile, 512 blocks): bf16 h chain ----------------
__global__ __launch_bounds__(256) void inl_step_mfma(
    const unsigned short* __restrict__ hbf_in, const unsigned short* __restrict__ Wbf,
    const float* __restrict__ bias, unsigned short* __restrict__ hbf_out) {
  __shared__ __align__(16) unsigned short ldsA[64 * 32];
  __shared__ __align__(16) unsigned short ldsB[128 * 32];
  int bm = blockIdx.y * 64, bn = blockIdx.x * 128;
  f32x4 acc[8];
  #pragma unroll
  for (int t = 0; t < 8; ++t) acc[t] = (f32x4){0.f, 0.f, 0.f, 0.f};
  gemm_nt_core<64, 128, 1, 4>(hbf_in + (size_t)bm * 512,
                              Wbf + (size_t)bn * 512, ldsA, ldsB, acc);
  int tid = threadIdx.x, w = tid >> 6, lane = tid & 63, quad = lane >> 4, l15 = lane & 15;
  #pragma unroll
  for (int i = 0; i < 4; ++i) {
    #pragma unroll
    for (int j = 0; j < 2; ++j) {
      int m0 = bm + i * 16 + quad * 4;
      int o = bn + w * 32 + j * 16 + l15;
      float bv = bias[o];
      f32x4 v = acc[i * 2 + j];
      #pragma unroll
      for (int r = 0; r < 4; ++r) {
        size_t idx = (size_t)(m0 + r) * 512 + o;
        float hin = bf2f(hbf_in[idx]);
        hbf_out[idx] = f2bf_fast(hin + DT_STEP * fast_tanh(v[r] + bv));
      }
    }
  }
}

// ---------------- Proj (64x128 tile, 512 blocks) + residual ----------------
__global__ __launch_bounds__(256) void gemm_proj_mfma(
    const unsigned short* __restrict__ Wbf, const unsigned short* __restrict__ hbf,
    const float* __restrict__ pb, const float* __restrict__ x,
    float* __restrict__ Out) {
  __shared__ __align__(16) unsigned short ldsA[64 * 32];
  __shared__ __align__(16) unsigned short ldsB[128 * 32];
  int bm = blockIdx.y * 64, bn = blockIdx.x * 128;
  f32x4 acc[8];
  #pragma unroll
  for (int t = 0; t < 8; ++t) acc[t] = (f32x4){0.f, 0.f, 0.f, 0.f};
  gemm_nt_core<64, 128, 1, 4>(Wbf + (size_t)bm * 512,
                              hbf + (size_t)bn * 512, ldsA, ldsB, acc);
  int tid = threadIdx.x, w = tid >> 6, lane = tid & 63, quad = lane >> 4, l15 = lane & 15;
  #pragma unroll
  for (int i = 0; i < 4; ++i) {
    #pragma unroll
    for (int j = 0; j < 2; ++j) {
      int o0 = bm + i * 16 + quad * 4;
      int ng = bn + w * 32 + j * 16 + l15;
      int b = ng >> 10, s = ng & 1023;
      f32x4 v = acc[i * 2 + j];
      #pragma unroll
      for (int r = 0; r < 4; ++r) {
        size_t idx = ((size_t)b * C_ + o0 + r) * S_ + s;
        Out[idx] = x[idx] + pb[o0 + r] + v[r];
      }
    }
  }
}

extern "C" void kernel_launch(void* const* d_in, const int* in_sizes, int n_in,
                              void* d_out, int out_size, void* d_ws, size_t ws_size,
                              hipStream_t stream) {
  const float* x        = (const float*)d_in[0];
  const float* gn_scale = (const float*)d_in[1];
  const float* gn_bias  = (const float*)d_in[2];
  const float* qkv_w    = (const float*)d_in[3];
  const float* qkv_b    = (const float*)d_in[4];
  const float* proj_w   = (const float*)d_in[5];
  const float* proj_b   = (const float*)d_in[6];
  const float* inl_w    = (const float*)d_in[7];
  const float* inl_b    = (const float*)d_in[8];
  float* out = (float*)d_out;
  float* ws = (float*)d_ws;

  // ws layout (float offsets):
  //   [8M,10M)  Qt bf16, [10M,12M) Kt bf16, [12M,14M) Vt bf16
  //   [14M,16M) h_t bf16 [B,S,C]  (dead after QKV; reused as Bbf)
  //   [16M,18M) Abf bf16
  //   [18M,+)   gpart, bf16 weights
  unsigned short* Qt  = (unsigned short*)(ws + 8388608);
  unsigned short* Kt  = (unsigned short*)(ws + 10485760);
  unsigned short* Vt  = (unsigned short*)(ws + 12582912);
  unsigned short* h_t = (unsigned short*)(ws + 14680064);
  unsigned short* Bbf = h_t;
  unsigned short* Abf = (unsigned short*)(ws + 16777216);
  float* gpart = ws + 18874368;
  unsigned short* qkvw_bf  = (unsigned short*)(ws + 18878464);
  unsigned short* inlw_bf  = qkvw_bf + 786432;
  unsigned short* projw_bf = inlw_bf + 262144;

  prep_kernel<<<1152, 256, 0, stream>>>(qkv_w, inl_w, proj_w, qkvw_bf, inlw_bf, projw_bf, x, gpart);
  gn_apply_t<<<1024, 256, 0, stream>>>(x, gpart, gn_scale, gn_bias, h_t);
  gemm_qkv_mfma<<<dim3(8, 12, 8), 256, 0, stream>>>(qkvw_bf, h_t, qkv_b, Qt, Kt, Vt);
  attn_mfma<<<1024, 256, 0, stream>>>(Qt, Kt, Vt, Abf);
  inl_step_mfma<<<dim3(4, 128), 256, 0, stream>>>(Abf, inlw_bf, inl_b, Bbf);
  inl_step_mfma<<<dim3(4, 128), 256, 0, stream>>>(Bbf, inlw_bf, inl_b, Abf);
  inl_step_mfma<<<dim3(4, 128), 256, 0, stream>>>(Abf, inlw_bf, inl_b, Bbf);
  gemm_proj_mfma<<<dim3(64, 8), 256, 0, stream>>>(projw_bf, Bbf, proj_b, x, out);
}

// Round 11
// 216.036 us; speedup vs baseline: 1.0617x; 1.0098x over previous
//
#include <hip/hip_runtime.h>
#include <math.h>

#define B_ 8
#define C_ 512
#define S_ 1024
#define HD 64
#define NHEADS 8
#define NGROUPS 8
#define DT_STEP 0.1f
#define EPS_GN 1e-5f
#define LOG2E 1.4426950408889634f

typedef __attribute__((ext_vector_type(8))) short bf16x8;
typedef __attribute__((ext_vector_type(4))) float f32x4;
typedef __attribute__((ext_vector_type(8))) unsigned short ushort8;
typedef __attribute__((ext_vector_type(4))) unsigned short ushort4_t;

static __device__ __forceinline__ unsigned short f2bf(float f) {     // RNE (cold paths)
  unsigned int u = __builtin_bit_cast(unsigned int, f);
  u += 0x7fff + ((u >> 16) & 1);
  return (unsigned short)(u >> 16);
}

static __device__ __forceinline__ unsigned short f2bf_fast(float f) { // round-half-up (hot paths)
  unsigned int u = __builtin_bit_cast(unsigned int, f);
  return (unsigned short)((u + 0x8000u) >> 16);
}

static __device__ __forceinline__ float bf2f(unsigned short u) {
  unsigned int t = ((unsigned int)u) << 16;
  return __builtin_bit_cast(float, t);
}

static __device__ __forceinline__ float exp2_raw(float x) {
  return __builtin_amdgcn_exp2f(x);    // single v_exp_f32, no libm guards
}

static __device__ __forceinline__ float fast_tanh(float x) {
  float xc = fminf(fmaxf(x, -15.f), 15.f);
  float e = exp2_raw(xc * (2.0f * LOG2E));
  return (e - 1.f) / (e + 1.f);
}

static __device__ __forceinline__ void load16_lds(const void* g, void* l) {
  __builtin_amdgcn_global_load_lds((const __attribute__((address_space(1))) void*)g,
                                   (__attribute__((address_space(3))) void*)l, 16, 0, 0);
}

// ---------------- prep: cast fp32 weights -> bf16  +  GroupNorm partial sums ----------------
__global__ __launch_bounds__(256) void prep_kernel(
    const float* __restrict__ a, const float* __restrict__ b, const float* __restrict__ c,
    unsigned short* __restrict__ A, unsigned short* __restrict__ B, unsigned short* __restrict__ C,
    const float* __restrict__ x, float* __restrict__ gpart) {
  int bid = blockIdx.x;
  int tid = threadIdx.x;
  if (bid < 640) {
    const float* src; unsigned short* dst; int off;
    if (bid < 384) { src = a; dst = A; off = bid * 2048; }
    else if (bid < 512) { src = b; dst = B; off = (bid - 384) * 2048; }
    else { src = c; dst = C; off = (bid - 512) * 2048; }
    int i = off + tid * 8;
    f32x4 v0 = *(const f32x4*)(src + i);
    f32x4 v1 = *(const f32x4*)(src + i + 4);
    ushort8 o;
    o[0] = f2bf(v0[0]); o[1] = f2bf(v0[1]); o[2] = f2bf(v0[2]); o[3] = f2bf(v0[3]);
    o[4] = f2bf(v1[0]); o[5] = f2bf(v1[1]); o[6] = f2bf(v1[2]); o[7] = f2bf(v1[3]);
    *(ushort8*)(dst + i) = o;
    return;
  }
  int sbid = bid - 640;
  int bg = sbid >> 3, chunk = sbid & 7;
  const float* xp = x + (size_t)bg * 65536 + (size_t)chunk * 8192;
  float sum = 0.f, sq = 0.f;
  #pragma unroll
  for (int i = 0; i < 8; ++i) {
    f32x4 v = *(const f32x4*)(xp + i * 1024 + tid * 4);
    sum += v[0] + v[1] + v[2] + v[3];
    sq += v[0]*v[0] + v[1]*v[1] + v[2]*v[2] + v[3]*v[3];
  }
  #pragma unroll
  for (int off = 32; off >= 1; off >>= 1) {
    sum += __shfl_xor(sum, off, 64);
    sq  += __shfl_xor(sq, off, 64);
  }
  __shared__ float s1[4], s2[4];
  int wave = tid >> 6, lane = tid & 63;
  if (lane == 0) { s1[wave] = sum; s2[wave] = sq; }
  __syncthreads();
  if (tid == 0) {
    float S = s1[0] + s1[1] + s1[2] + s1[3];
    float Q = s2[0] + s2[1] + s2[2] + s2[3];
    gpart[bg * 16 + chunk * 2] = S;
    gpart[bg * 16 + chunk * 2 + 1] = Q;
  }
}

// ---------------- GroupNorm pass 2: normalize + transpose to h_t[B,S,C] bf16 ----------------
__global__ __launch_bounds__(256) void gn_apply_t(
    const float* __restrict__ x, const float* __restrict__ gpart,
    const float* __restrict__ scale, const float* __restrict__ bias,
    unsigned short* __restrict__ h_t) {
  int bid = blockIdx.x;
  int bg = bid >> 4, st = bid & 15;
  int b = bg >> 3, g = bg & 7;
  float S = 0.f, Q = 0.f;
  #pragma unroll
  for (int i = 0; i < 8; ++i) {
    S += gpart[bg * 16 + i * 2];
    Q += gpart[bg * 16 + i * 2 + 1];
  }
  float mean = S / 65536.f;
  float var = Q / 65536.f - mean * mean;
  float inv = rsqrtf(var + EPS_GN);

  int tid = threadIdx.x;
  int sl = tid >> 2;
  int cq = (tid & 3) * 16;
  float sA[16], sB[16];
  #pragma unroll
  for (int u = 0; u < 16; ++u) {
    float scv = scale[g * 64 + cq + u];
    sA[u] = inv * scv;
    sB[u] = bias[g * 64 + cq + u] - mean * inv * scv;
  }

  const float* xp = x + ((size_t)b * C_ + (size_t)g * 64) * S_;
  __shared__ float tile[64][65];
  #pragma unroll
  for (int it = 0; it < 16; ++it) {
    int lin = it * 256 + tid;
    int c = lin >> 6, s = lin & 63;
    tile[c][s] = xp[(size_t)c * S_ + st * 64 + s];
  }
  __syncthreads();
  unsigned short vals[16];
  #pragma unroll
  for (int u = 0; u < 16; ++u)
    vals[u] = f2bf_fast(tile[cq + u][sl] * sA[u] + sB[u]);
  unsigned short* dst = h_t + ((size_t)b * S_ + st * 64 + sl) * C_ + g * 64 + cq;
  ushort8 lo, hi;
  #pragma unroll
  for (int u = 0; u < 8; ++u) { lo[u] = vals[u]; hi[u] = vals[u + 8]; }
  *(ushort8*)dst = lo;
  *(ushort8*)(dst + 8) = hi;
}

// ---------------- NT GEMM core: C[MB,NB] = A[MB,512] * B[NB,512]^T ----------------
template<int MB, int NB, int WMG, int WNG>
__device__ __forceinline__ void gemm_nt_core(
    const unsigned short* __restrict__ Ab,
    const unsigned short* __restrict__ Bb,
    unsigned short* ldsA, unsigned short* ldsB,
    f32x4* acc) {
  constexpr int TI = (MB / WMG) / 16;
  constexpr int TJ = (NB / WNG) / 16;
  constexpr int NQA = MB * 4 / 256;
  constexpr int NQB = NB * 4 / 256;
  const int K = 512;
  const int tid = threadIdx.x;
  const int w = tid >> 6, lane = tid & 63, quad = lane >> 4, l15 = lane & 15;
  const int wm = (WNG == 1) ? w : ((WMG == 1) ? 0 : (w >> 1));
  const int wn = (WNG == 1) ? 0 : ((WMG == 1) ? w : (w & 1));

  for (int k0 = 0; k0 < K; k0 += 32) {
    __syncthreads();
    #pragma unroll
    for (int q = 0; q < NQA; ++q) {
      int c = q * 256 + tid;
      load16_lds(Ab + (size_t)(c >> 2) * K + k0 + (c & 3) * 8, ldsA + c * 8);
    }
    #pragma unroll
    for (int q = 0; q < NQB; ++q) {
      int c = q * 256 + tid;
      load16_lds(Bb + (size_t)(c >> 2) * K + k0 + (c & 3) * 8, ldsB + c * 8);
    }
    __syncthreads();
    bf16x8 af[TI], bfr[TJ];
    #pragma unroll
    for (int i = 0; i < TI; ++i)
      af[i] = *(const bf16x8*)(ldsA + (wm * (MB / WMG) + i * 16 + l15) * 32 + quad * 8);
    #pragma unroll
    for (int j = 0; j < TJ; ++j)
      bfr[j] = *(const bf16x8*)(ldsB + (wn * (NB / WNG) + j * 16 + l15) * 32 + quad * 8);
    #pragma unroll
    for (int i = 0; i < TI; ++i)
      #pragma unroll
      for (int j = 0; j < TJ; ++j)
        acc[i * TJ + j] = __builtin_amdgcn_mfma_f32_16x16x32_bf16(af[i], bfr[j], acc[i * TJ + j], 0, 0, 0);
  }
}

// ---------------- QKV GEMM: W_bf[1536,512] x h_t[b][1024,512]^T ----------------
// Q pre-scaled by hd^-0.5 * log2(e) so attention uses raw v_exp.
__global__ __launch_bounds__(256) void gemm_qkv_mfma(
    const unsigned short* __restrict__ Wbf, const unsigned short* __restrict__ h_t,
    const float* __restrict__ bias,
    unsigned short* __restrict__ Qt, unsigned short* __restrict__ Kt,
    unsigned short* __restrict__ Vt) {
  __shared__ __align__(16) unsigned short ldsA[128 * 32];
  __shared__ __align__(16) unsigned short ldsB[128 * 32];
  int b = blockIdx.z;
  int bm = blockIdx.y * 128, bn = blockIdx.x * 128;
  f32x4 acc[16];
  #pragma unroll
  for (int t = 0; t < 16; ++t) acc[t] = (f32x4){0.f, 0.f, 0.f, 0.f};
  gemm_nt_core<128, 128, 2, 2>(Wbf + (size_t)bm * 512,
                               h_t + ((size_t)b * S_ + bn) * 512, ldsA, ldsB, acc);
  int tid = threadIdx.x, w = tid >> 6, lane = tid & 63, quad = lane >> 4, l15 = lane & 15;
  int wm = w >> 1, wn = w & 1;
  int tensor = bm >> 9;
  float qscale = (tensor == 0) ? 0.125f * LOG2E : 1.0f;
  #pragma unroll
  for (int i = 0; i < 4; ++i) {
    #pragma unroll
    for (int j = 0; j < 4; ++j) {
      int m0 = bm + wm * 64 + i * 16 + quad * 4;
      int ng = bn + wn * 64 + j * 16 + l15;
      f32x4 v = acc[i * 4 + j];
      if (tensor < 2) {
        int head = (m0 >> 6) & 7, d0 = m0 & 63;
        ushort4_t pk;
        #pragma unroll
        for (int r = 0; r < 4; ++r) pk[r] = f2bf((v[r] + bias[m0 + r]) * qscale);
        unsigned short* dst = (tensor ? Kt : Qt) +
            (((size_t)(b * 8 + head) * S_ + ng) * 64 + d0);
        *(ushort4_t*)dst = pk;
      } else {
        #pragma unroll
        for (int r = 0; r < 4; ++r)
          Vt[(size_t)b * (C_ * S_) + (size_t)(m0 - 1024 + r) * S_ + ng] = f2bf(v[r] + bias[m0 + r]);
      }
    }
  }
}

// ---------------- Flash attention: bf16 MFMA, no-max base-2 softmax, reg-prefetched K/V ----------------
// grid 1024: bid = sblk*64 + (b*8+n); 4 waves x 16 q-rows
__global__ __launch_bounds__(256) void attn_mfma(
    const unsigned short* __restrict__ Qt,   // [B][NH][S][HD] (pre-scaled, incl log2e)
    const unsigned short* __restrict__ Kt,
    const unsigned short* __restrict__ Vt,   // [B][C][S]
    unsigned short* __restrict__ hflat_bf) { // [B][S][C] bf16
  int tid = threadIdx.x, wave = tid >> 6, lane = tid & 63;
  int quad = lane >> 4, l15 = lane & 15;
  int bid = blockIdx.x;
  int bn = bid & 63, sblk = bid >> 6, b = bn >> 3, n = bn & 7;
  int s0w = sblk * 64 + wave * 16;

  __shared__ unsigned short k_lds[64][72];
  __shared__ unsigned short v_lds[64][72];
  __shared__ unsigned short p_lds[4][16][72];

  const unsigned short* Qb = Qt + (((size_t)(b * 8 + n)) * S_ + s0w + l15) * 64;
  const unsigned short* Kb = Kt + ((size_t)(b * 8 + n)) * S_ * 64;
  const unsigned short* Vb = Vt + ((size_t)b * C_ + n * 64) * S_;

  bf16x8 qa0 = *(const bf16x8*)(Qb + quad * 8);
  bf16x8 qa1 = *(const bf16x8*)(Qb + 32 + quad * 8);

  bf16x8 ones;
  #pragma unroll
  for (int j = 0; j < 8; ++j) ones[j] = (short)0x3F80;

  f32x4 o_acc[4];
  f32x4 l_acc = {0.f, 0.f, 0.f, 0.f};
  #pragma unroll
  for (int dc = 0; dc < 4; ++dc) o_acc[dc] = (f32x4){0.f, 0.f, 0.f, 0.f};

  // staging geometry: thread handles chunks idx = tid + it*256 (row=idx>>3, c8=(idx&7)*8)
  int row0 = tid >> 3, c80 = (tid & 7) * 8;
  int row1 = (tid + 256) >> 3, c81 = c80;

  // prefetch tile 0 into registers
  ushort8 kreg[2], vreg[2];
  kreg[0] = *(const ushort8*)(Kb + (size_t)row0 * 64 + c80);
  kreg[1] = *(const ushort8*)(Kb + (size_t)row1 * 64 + c81);
  vreg[0] = *(const ushort8*)(Vb + (size_t)row0 * S_ + c80);
  vreg[1] = *(const ushort8*)(Vb + (size_t)row1 * S_ + c81);

  for (int t0 = 0; t0 < S_; t0 += 64) {
    __syncthreads();                         // prior tile fully consumed
    *(ushort8*)&k_lds[row0][c80] = kreg[0];
    *(ushort8*)&k_lds[row1][c81] = kreg[1];
    *(ushort8*)&v_lds[row0][c80] = vreg[0];
    *(ushort8*)&v_lds[row1][c81] = vreg[1];
    __syncthreads();
    if (t0 + 64 < S_) {                      // issue next-tile loads; waited next iter
      int t1 = t0 + 64;
      kreg[0] = *(const ushort8*)(Kb + (size_t)(t1 + row0) * 64 + c80);
      kreg[1] = *(const ushort8*)(Kb + (size_t)(t1 + row1) * 64 + c81);
      vreg[0] = *(const ushort8*)(Vb + (size_t)row0 * S_ + t1 + c80);
      vreg[1] = *(const ushort8*)(Vb + (size_t)row1 * S_ + t1 + c81);
    }

    f32x4 sc[4];
    #pragma unroll
    for (int tc = 0; tc < 4; ++tc) {
      bf16x8 kb0 = *(const bf16x8*)&k_lds[tc * 16 + l15][quad * 8];
      bf16x8 kb1 = *(const bf16x8*)&k_lds[tc * 16 + l15][32 + quad * 8];
      f32x4 c = {0.f, 0.f, 0.f, 0.f};
      c = __builtin_amdgcn_mfma_f32_16x16x32_bf16(qa0, kb0, c, 0, 0, 0);
      sc[tc] = __builtin_amdgcn_mfma_f32_16x16x32_bf16(qa1, kb1, c, 0, 0, 0);
    }

    // P = 2^score via raw v_exp (Q carries 1/sqrt(hd)*log2e; scores bounded, fp32-safe)
    #pragma unroll
    for (int tc = 0; tc < 4; ++tc)
      #pragma unroll
      for (int r = 0; r < 4; ++r)
        p_lds[wave][quad * 4 + r][tc * 16 + l15] = f2bf_fast(exp2_raw(sc[tc][r]));

    bf16x8 pa0 = *(const bf16x8*)&p_lds[wave][l15][quad * 8];
    bf16x8 pa1 = *(const bf16x8*)&p_lds[wave][l15][32 + quad * 8];
    l_acc = __builtin_amdgcn_mfma_f32_16x16x32_bf16(pa0, ones, l_acc, 0, 0, 0);
    l_acc = __builtin_amdgcn_mfma_f32_16x16x32_bf16(pa1, ones, l_acc, 0, 0, 0);
    #pragma unroll
    for (int dc = 0; dc < 4; ++dc) {
      bf16x8 vb0 = *(const bf16x8*)&v_lds[dc * 16 + l15][quad * 8];
      bf16x8 vb1 = *(const bf16x8*)&v_lds[dc * 16 + l15][32 + quad * 8];
      o_acc[dc] = __builtin_amdgcn_mfma_f32_16x16x32_bf16(pa0, vb0, o_acc[dc], 0, 0, 0);
      o_acc[dc] = __builtin_amdgcn_mfma_f32_16x16x32_bf16(pa1, vb1, o_acc[dc], 0, 0, 0);
    }
  }

  float inv_l[4];
  #pragma unroll
  for (int r = 0; r < 4; ++r) inv_l[r] = 1.f / l_acc[r];
  #pragma unroll
  for (int dc = 0; dc < 4; ++dc) {
    #pragma unroll
    for (int r = 0; r < 4; ++r) {
      int s = s0w + quad * 4 + r;
      size_t idx = ((size_t)b * S_ + s) * C_ + n * 64 + dc * 16 + l15;
      hflat_bf[idx] = f2bf_fast(o_acc[dc][r] * inv_l[r]);
    }
  }
}

// ---------------- INL step (64x64 tile, 1024 blocks = 4/CU): bf16 h chain ----------------
// grid (8, 128): bm = by*64 (s-rows), bn = bx*64 (out channels)
__global__ __launch_bounds__(256) void inl_step_mfma(
    const unsigned short* __restrict__ hbf_in, const unsigned short* __restrict__ Wbf,
    const float* __restrict__ bias, unsigned short* __restrict__ hbf_out) {
  __shared__ __align__(16) unsigned short ldsA[64 * 32];
  __shared__ __align__(16) unsigned short ldsB[64 * 32];
  int bm = blockIdx.y * 64, bn = blockIdx.x * 64;
  f32x4 acc[4];
  #pragma unroll
  for (int t = 0; t < 4; ++t) acc[t] = (f32x4){0.f, 0.f, 0.f, 0.f};
  gemm_nt_core<64, 64, 2, 2>(hbf_in + (size_t)bm * 512,
                             Wbf + (size_t)bn * 512, ldsA, ldsB, acc);
  int tid = threadIdx.x, w = tid >> 6, lane = tid & 63, quad = lane >> 4, l15 = lane & 15;
  int wm = w >> 1, wn = w & 1;
  #pragma unroll
  for (int i = 0; i < 2; ++i) {
    #pragma unroll
    for (int j = 0; j < 2; ++j) {
      int m0 = bm + wm * 32 + i * 16 + quad * 4;
      int o = bn + wn * 32 + j * 16 + l15;
      float bv = bias[o];
      f32x4 v = acc[i * 2 + j];
      #pragma unroll
      for (int r = 0; r < 4; ++r) {
        size_t idx = (size_t)(m0 + r) * 512 + o;
        float hin = bf2f(hbf_in[idx]);
        hbf_out[idx] = f2bf_fast(hin + DT_STEP * fast_tanh(v[r] + bv));
      }
    }
  }
}

// ---------------- Proj (64x64 tile, 1024 blocks) + residual ----------------
// grid (128, 8): bm = by*64 (o), bn = bx*64 (s-global)
__global__ __launch_bounds__(256) void gemm_proj_mfma(
    const unsigned short* __restrict__ Wbf, const unsigned short* __restrict__ hbf,
    const float* __restrict__ pb, const float* __restrict__ x,
    float* __restrict__ Out) {
  __shared__ __align__(16) unsigned short ldsA[64 * 32];
  __shared__ __align__(16) unsigned short ldsB[64 * 32];
  int bm = blockIdx.y * 64, bn = blockIdx.x * 64;
  f32x4 acc[4];
  #pragma unroll
  for (int t = 0; t < 4; ++t) acc[t] = (f32x4){0.f, 0.f, 0.f, 0.f};
  gemm_nt_core<64, 64, 2, 2>(Wbf + (size_t)bm * 512,
                             hbf + (size_t)bn * 512, ldsA, ldsB, acc);
  int tid = threadIdx.x, w = tid >> 6, lane = tid & 63, quad = lane >> 4, l15 = lane & 15;
  int wm = w >> 1, wn = w & 1;
  #pragma unroll
  for (int i = 0; i < 2; ++i) {
    #pragma unroll
    for (int j = 0; j < 2; ++j) {
      int o0 = bm + wm * 32 + i * 16 + quad * 4;
      int ng = bn + wn * 32 + j * 16 + l15;
      int b = ng >> 10, s = ng & 1023;
      f32x4 v = acc[i * 2 + j];
      #pragma unroll
      for (int r = 0; r < 4; ++r) {
        size_t idx = ((size_t)b * C_ + o0 + r) * S_ + s;
        Out[idx] = x[idx] + pb[o0 + r] + v[r];
      }
    }
  }
}

extern "C" void kernel_launch(void* const* d_in, const int* in_sizes, int n_in,
                              void* d_out, int out_size, void* d_ws, size_t ws_size,
                              hipStream_t stream) {
  const float* x        = (const float*)d_in[0];
  const float* gn_scale = (const float*)d_in[1];
  const float* gn_bias  = (const float*)d_in[2];
  const float* qkv_w    = (const float*)d_in[3];
  const float* qkv_b    = (const float*)d_in[4];
  const float* proj_w   = (const float*)d_in[5];
  const float* proj_b   = (const float*)d_in[6];
  const float* inl_w    = (const float*)d_in[7];
  const float* inl_b    = (const float*)d_in[8];
  float* out = (float*)d_out;
  float* ws = (float*)d_ws;

  // ws layout (float offsets):
  //   [8M,10M)  Qt bf16, [10M,12M) Kt bf16, [12M,14M) Vt bf16
  //   [14M,16M) h_t bf16 [B,S,C]  (dead after QKV; reused as Bbf)
  //   [16M,18M) Abf bf16
  //   [18M,+)   gpart, bf16 weights
  unsigned short* Qt  = (unsigned short*)(ws + 8388608);
  unsigned short* Kt  = (unsigned short*)(ws + 10485760);
  unsigned short* Vt  = (unsigned short*)(ws + 12582912);
  unsigned short* h_t = (unsigned short*)(ws + 14680064);
  unsigned short* Bbf = h_t;
  unsigned short* Abf = (unsigned short*)(ws + 16777216);
  float* gpart = ws + 18874368;
  unsigned short* qkvw_bf  = (unsigned short*)(ws + 18878464);
  unsigned short* inlw_bf  = qkvw_bf + 786432;
  unsigned short* projw_bf = inlw_bf + 262144;

  prep_kernel<<<1152, 256, 0, stream>>>(qkv_w, inl_w, proj_w, qkvw_bf, inlw_bf, projw_bf, x, gpart);
  gn_apply_t<<<1024, 256, 0, stream>>>(x, gpart, gn_scale, gn_bias, h_t);
  gemm_qkv_mfma<<<dim3(8, 12, 8), 256, 0, stream>>>(qkvw_bf, h_t, qkv_b, Qt, Kt, Vt);
  attn_mfma<<<1024, 256, 0, stream>>>(Qt, Kt, Vt, Abf);
  inl_step_mfma<<<dim3(8, 128), 256, 0, stream>>>(Abf, inlw_bf, inl_b, Bbf);
  inl_step_mfma<<<dim3(8, 128), 256, 0, stream>>>(Bbf, inlw_bf, inl_b, Abf);
  inl_step_mfma<<<dim3(8, 128), 256, 0, stream>>>(Abf, inlw_bf, inl_b, Bbf);
  gemm_proj_mfma<<<dim3(128, 8), 256, 0, stream>>>(projw_bf, Bbf, proj_b, x, out);
}

// Round 12
// 208.920 us; speedup vs baseline: 1.0978x; 1.0341x over previous
//
#include <hip/hip_runtime.h>
#include <math.h>

#define B_ 8
#define C_ 512
#define S_ 1024
#define HD 64
#define NHEADS 8
#define NGROUPS 8
#define DT_STEP 0.1f
#define EPS_GN 1e-5f
#define LOG2E 1.4426950408889634f

typedef __attribute__((ext_vector_type(8))) short bf16x8;
typedef __attribute__((ext_vector_type(4))) float f32x4;
typedef __attribute__((ext_vector_type(8))) unsigned short ushort8;
typedef __attribute__((ext_vector_type(4))) unsigned short ushort4_t;

static __device__ __forceinline__ unsigned short f2bf(float f) {     // RNE (cold paths)
  unsigned int u = __builtin_bit_cast(unsigned int, f);
  u += 0x7fff + ((u >> 16) & 1);
  return (unsigned short)(u >> 16);
}

static __device__ __forceinline__ unsigned short f2bf_fast(float f) { // round-half-up (hot paths)
  unsigned int u = __builtin_bit_cast(unsigned int, f);
  return (unsigned short)((u + 0x8000u) >> 16);
}

static __device__ __forceinline__ float bf2f(unsigned short u) {
  unsigned int t = ((unsigned int)u) << 16;
  return __builtin_bit_cast(float, t);
}

static __device__ __forceinline__ float exp2_raw(float x) {
  return __builtin_amdgcn_exp2f(x);    // single v_exp_f32
}

static __device__ __forceinline__ float fast_tanh(float x) {
  float xc = fminf(fmaxf(x, -15.f), 15.f);
  float e = exp2_raw(xc * (2.0f * LOG2E));
  return (e - 1.f) / (e + 1.f);
}

static __device__ __forceinline__ void load16_lds(const void* g, void* l) {
  __builtin_amdgcn_global_load_lds((const __attribute__((address_space(1))) void*)g,
                                   (__attribute__((address_space(3))) void*)l, 16, 0, 0);
}

// ---------------- prep: cast fp32 weights -> bf16  +  GroupNorm partial sums ----------------
__global__ __launch_bounds__(256) void prep_kernel(
    const float* __restrict__ a, const float* __restrict__ b, const float* __restrict__ c,
    unsigned short* __restrict__ A, unsigned short* __restrict__ B, unsigned short* __restrict__ C,
    const float* __restrict__ x, float* __restrict__ gpart) {
  int bid = blockIdx.x;
  int tid = threadIdx.x;
  if (bid < 640) {
    const float* src; unsigned short* dst; int off;
    if (bid < 384) { src = a; dst = A; off = bid * 2048; }
    else if (bid < 512) { src = b; dst = B; off = (bid - 384) * 2048; }
    else { src = c; dst = C; off = (bid - 512) * 2048; }
    int i = off + tid * 8;
    f32x4 v0 = *(const f32x4*)(src + i);
    f32x4 v1 = *(const f32x4*)(src + i + 4);
    ushort8 o;
    o[0] = f2bf(v0[0]); o[1] = f2bf(v0[1]); o[2] = f2bf(v0[2]); o[3] = f2bf(v0[3]);
    o[4] = f2bf(v1[0]); o[5] = f2bf(v1[1]); o[6] = f2bf(v1[2]); o[7] = f2bf(v1[3]);
    *(ushort8*)(dst + i) = o;
    return;
  }
  int sbid = bid - 640;
  int bg = sbid >> 3, chunk = sbid & 7;
  const float* xp = x + (size_t)bg * 65536 + (size_t)chunk * 8192;
  float sum = 0.f, sq = 0.f;
  #pragma unroll
  for (int i = 0; i < 8; ++i) {
    f32x4 v = *(const f32x4*)(xp + i * 1024 + tid * 4);
    sum += v[0] + v[1] + v[2] + v[3];
    sq += v[0]*v[0] + v[1]*v[1] + v[2]*v[2] + v[3]*v[3];
  }
  #pragma unroll
  for (int off = 32; off >= 1; off >>= 1) {
    sum += __shfl_xor(sum, off, 64);
    sq  += __shfl_xor(sq, off, 64);
  }
  __shared__ float s1[4], s2[4];
  int wave = tid >> 6, lane = tid & 63;
  if (lane == 0) { s1[wave] = sum; s2[wave] = sq; }
  __syncthreads();
  if (tid == 0) {
    float S = s1[0] + s1[1] + s1[2] + s1[3];
    float Q = s2[0] + s2[1] + s2[2] + s2[3];
    gpart[bg * 16 + chunk * 2] = S;
    gpart[bg * 16 + chunk * 2 + 1] = Q;
  }
}

// ---------------- GroupNorm pass 2: normalize + transpose to h_t[B,S,C] bf16 ----------------
__global__ __launch_bounds__(256) void gn_apply_t(
    const float* __restrict__ x, const float* __restrict__ gpart,
    const float* __restrict__ scale, const float* __restrict__ bias,
    unsigned short* __restrict__ h_t) {
  int bid = blockIdx.x;
  int bg = bid >> 4, st = bid & 15;
  int b = bg >> 3, g = bg & 7;
  float S = 0.f, Q = 0.f;
  #pragma unroll
  for (int i = 0; i < 8; ++i) {
    S += gpart[bg * 16 + i * 2];
    Q += gpart[bg * 16 + i * 2 + 1];
  }
  float mean = S / 65536.f;
  float var = Q / 65536.f - mean * mean;
  float inv = rsqrtf(var + EPS_GN);

  int tid = threadIdx.x;
  int sl = tid >> 2;
  int cq = (tid & 3) * 16;
  float sA[16], sB[16];
  #pragma unroll
  for (int u = 0; u < 16; ++u) {
    float scv = scale[g * 64 + cq + u];
    sA[u] = inv * scv;
    sB[u] = bias[g * 64 + cq + u] - mean * inv * scv;
  }

  const float* xp = x + ((size_t)b * C_ + (size_t)g * 64) * S_;
  __shared__ float tile[64][65];
  #pragma unroll
  for (int it = 0; it < 16; ++it) {
    int lin = it * 256 + tid;
    int c = lin >> 6, s = lin & 63;
    tile[c][s] = xp[(size_t)c * S_ + st * 64 + s];
  }
  __syncthreads();
  unsigned short vals[16];
  #pragma unroll
  for (int u = 0; u < 16; ++u)
    vals[u] = f2bf_fast(tile[cq + u][sl] * sA[u] + sB[u]);
  unsigned short* dst = h_t + ((size_t)b * S_ + st * 64 + sl) * C_ + g * 64 + cq;
  ushort8 lo, hi;
  #pragma unroll
  for (int u = 0; u < 8; ++u) { lo[u] = vals[u]; hi[u] = vals[u + 8]; }
  *(ushort8*)dst = lo;
  *(ushort8*)(dst + 8) = hi;
}

// ---------------- NT GEMM core: C[MB,NB] = A[MB,512] * B[NB,512]^T ----------------
template<int MB, int NB, int WMG, int WNG>
__device__ __forceinline__ void gemm_nt_core(
    const unsigned short* __restrict__ Ab,
    const unsigned short* __restrict__ Bb,
    unsigned short* ldsA, unsigned short* ldsB,
    f32x4* acc) {
  constexpr int TI = (MB / WMG) / 16;
  constexpr int TJ = (NB / WNG) / 16;
  constexpr int NQA = MB * 4 / 256;
  constexpr int NQB = NB * 4 / 256;
  const int K = 512;
  const int tid = threadIdx.x;
  const int w = tid >> 6, lane = tid & 63, quad = lane >> 4, l15 = lane & 15;
  const int wm = (WNG == 1) ? w : ((WMG == 1) ? 0 : (w >> 1));
  const int wn = (WNG == 1) ? 0 : ((WMG == 1) ? w : (w & 1));

  for (int k0 = 0; k0 < K; k0 += 32) {
    __syncthreads();
    #pragma unroll
    for (int q = 0; q < NQA; ++q) {
      int c = q * 256 + tid;
      load16_lds(Ab + (size_t)(c >> 2) * K + k0 + (c & 3) * 8, ldsA + c * 8);
    }
    #pragma unroll
    for (int q = 0; q < NQB; ++q) {
      int c = q * 256 + tid;
      load16_lds(Bb + (size_t)(c >> 2) * K + k0 + (c & 3) * 8, ldsB + c * 8);
    }
    __syncthreads();
    bf16x8 af[TI], bfr[TJ];
    #pragma unroll
    for (int i = 0; i < TI; ++i)
      af[i] = *(const bf16x8*)(ldsA + (wm * (MB / WMG) + i * 16 + l15) * 32 + quad * 8);
    #pragma unroll
    for (int j = 0; j < TJ; ++j)
      bfr[j] = *(const bf16x8*)(ldsB + (wn * (NB / WNG) + j * 16 + l15) * 32 + quad * 8);
    #pragma unroll
    for (int i = 0; i < TI; ++i)
      #pragma unroll
      for (int j = 0; j < TJ; ++j)
        acc[i * TJ + j] = __builtin_amdgcn_mfma_f32_16x16x32_bf16(af[i], bfr[j], acc[i * TJ + j], 0, 0, 0);
  }
}

// ---------------- QKV GEMM: W_bf[1536,512] x h_t[b][1024,512]^T ----------------
__global__ __launch_bounds__(256) void gemm_qkv_mfma(
    const unsigned short* __restrict__ Wbf, const unsigned short* __restrict__ h_t,
    const float* __restrict__ bias,
    unsigned short* __restrict__ Qt, unsigned short* __restrict__ Kt,
    unsigned short* __restrict__ Vt) {
  __shared__ __align__(16) unsigned short ldsA[128 * 32];
  __shared__ __align__(16) unsigned short ldsB[128 * 32];
  int b = blockIdx.z;
  int bm = blockIdx.y * 128, bn = blockIdx.x * 128;
  f32x4 acc[16];
  #pragma unroll
  for (int t = 0; t < 16; ++t) acc[t] = (f32x4){0.f, 0.f, 0.f, 0.f};
  gemm_nt_core<128, 128, 2, 2>(Wbf + (size_t)bm * 512,
                               h_t + ((size_t)b * S_ + bn) * 512, ldsA, ldsB, acc);
  int tid = threadIdx.x, w = tid >> 6, lane = tid & 63, quad = lane >> 4, l15 = lane & 15;
  int wm = w >> 1, wn = w & 1;
  int tensor = bm >> 9;
  float qscale = (tensor == 0) ? 0.125f * LOG2E : 1.0f;
  #pragma unroll
  for (int i = 0; i < 4; ++i) {
    #pragma unroll
    for (int j = 0; j < 4; ++j) {
      int m0 = bm + wm * 64 + i * 16 + quad * 4;
      int ng = bn + wn * 64 + j * 16 + l15;
      f32x4 v = acc[i * 4 + j];
      if (tensor < 2) {
        int head = (m0 >> 6) & 7, d0 = m0 & 63;
        ushort4_t pk;
        #pragma unroll
        for (int r = 0; r < 4; ++r) pk[r] = f2bf((v[r] + bias[m0 + r]) * qscale);
        unsigned short* dst = (tensor ? Kt : Qt) +
            (((size_t)(b * 8 + head) * S_ + ng) * 64 + d0);
        *(ushort4_t*)dst = pk;
      } else {
        #pragma unroll
        for (int r = 0; r < 4; ++r)
          Vt[(size_t)b * (C_ * S_) + (size_t)(m0 - 1024 + r) * S_ + ng] = f2bf(v[r] + bias[m0 + r]);
      }
    }
  }
}

// ---------------- Flash attention: transposed scores, 2 q-groups/wave, reg-prefetched K/V ----------------
// grid 512: bid = sblk*64 + (b*8+n); 4 waves x 32 q-rows (2 groups of 16)
__global__ __launch_bounds__(256) void attn_mfma(
    const unsigned short* __restrict__ Qt,   // [B][NH][S][HD] (pre-scaled, incl log2e)
    const unsigned short* __restrict__ Kt,
    const unsigned short* __restrict__ Vt,   // [B][C][S]
    unsigned short* __restrict__ hflat_bf) { // [B][S][C] bf16
  int tid = threadIdx.x, wave = tid >> 6, lane = tid & 63;
  int quad = lane >> 4, l15 = lane & 15;
  int bid = blockIdx.x;
  int bn = bid & 63, sblk = bid >> 6, b = bn >> 3, n = bn & 7;
  int s0w = sblk * 128 + wave * 32;

  __shared__ unsigned short k_lds[64][72];
  __shared__ unsigned short v_lds[64][72];
  __shared__ unsigned short p_lds[4][2][16][72];  // [wave][group][s][t], A-layout

  const unsigned short* Kb = Kt + ((size_t)(b * 8 + n)) * S_ * 64;
  const unsigned short* Vb = Vt + ((size_t)b * C_ + n * 64) * S_;

  bf16x8 qa[2][2];
  #pragma unroll
  for (int g = 0; g < 2; ++g) {
    const unsigned short* Qb = Qt + (((size_t)(b * 8 + n)) * S_ + s0w + g * 16 + l15) * 64;
    qa[g][0] = *(const bf16x8*)(Qb + quad * 8);
    qa[g][1] = *(const bf16x8*)(Qb + 32 + quad * 8);
  }

  bf16x8 ones;
  #pragma unroll
  for (int j = 0; j < 8; ++j) ones[j] = (short)0x3F80;

  f32x4 o_acc[2][4];
  f32x4 l_acc[2];
  #pragma unroll
  for (int g = 0; g < 2; ++g) {
    l_acc[g] = (f32x4){0.f, 0.f, 0.f, 0.f};
    #pragma unroll
    for (int dc = 0; dc < 4; ++dc) o_acc[g][dc] = (f32x4){0.f, 0.f, 0.f, 0.f};
  }

  int row0 = tid >> 3, c80 = (tid & 7) * 8;
  int row1 = (tid + 256) >> 3, c81 = c80;

  ushort8 kreg[2], vreg[2];
  kreg[0] = *(const ushort8*)(Kb + (size_t)row0 * 64 + c80);
  kreg[1] = *(const ushort8*)(Kb + (size_t)row1 * 64 + c81);
  vreg[0] = *(const ushort8*)(Vb + (size_t)row0 * S_ + c80);
  vreg[1] = *(const ushort8*)(Vb + (size_t)row1 * S_ + c81);

  for (int t0 = 0; t0 < S_; t0 += 64) {
    __syncthreads();
    *(ushort8*)&k_lds[row0][c80] = kreg[0];
    *(ushort8*)&k_lds[row1][c81] = kreg[1];
    *(ushort8*)&v_lds[row0][c80] = vreg[0];
    *(ushort8*)&v_lds[row1][c81] = vreg[1];
    __syncthreads();
    if (t0 + 64 < S_) {
      int t1 = t0 + 64;
      kreg[0] = *(const ushort8*)(Kb + (size_t)(t1 + row0) * 64 + c80);
      kreg[1] = *(const ushort8*)(Kb + (size_t)(t1 + row1) * 64 + c81);
      vreg[0] = *(const ushort8*)(Vb + (size_t)row0 * S_ + t1 + c80);
      vreg[1] = *(const ushort8*)(Vb + (size_t)row1 * S_ + t1 + c81);
    }

    // Transposed scores: St[t][s] = sum_d K[t][d] Q[s][d]  (A=K-frag, B=Q-frag)
    // C-layout: row = t_local = quad*4+r (+tc*16), col = s_local = l15
    f32x4 sc[2][4];
    #pragma unroll
    for (int tc = 0; tc < 4; ++tc) {
      bf16x8 kb0 = *(const bf16x8*)&k_lds[tc * 16 + l15][quad * 8];
      bf16x8 kb1 = *(const bf16x8*)&k_lds[tc * 16 + l15][32 + quad * 8];
      #pragma unroll
      for (int g = 0; g < 2; ++g) {
        f32x4 c = {0.f, 0.f, 0.f, 0.f};
        c = __builtin_amdgcn_mfma_f32_16x16x32_bf16(kb0, qa[g][0], c, 0, 0, 0);
        sc[g][tc] = __builtin_amdgcn_mfma_f32_16x16x32_bf16(kb1, qa[g][1], c, 0, 0, 0);
      }
    }

    // exp -> P[s][t] in LDS via contiguous b64 writes (4 t-values per lane per tc)
    #pragma unroll
    for (int g = 0; g < 2; ++g)
      #pragma unroll
      for (int tc = 0; tc < 4; ++tc) {
        ushort4_t p4;
        #pragma unroll
        for (int r = 0; r < 4; ++r) p4[r] = f2bf_fast(exp2_raw(sc[g][tc][r]));
        *(ushort4_t*)&p_lds[wave][g][l15][tc * 16 + quad * 4] = p4;
      }

    bf16x8 pa[2][2];
    #pragma unroll
    for (int g = 0; g < 2; ++g) {
      pa[g][0] = *(const bf16x8*)&p_lds[wave][g][l15][quad * 8];
      pa[g][1] = *(const bf16x8*)&p_lds[wave][g][l15][32 + quad * 8];
      l_acc[g] = __builtin_amdgcn_mfma_f32_16x16x32_bf16(pa[g][0], ones, l_acc[g], 0, 0, 0);
      l_acc[g] = __builtin_amdgcn_mfma_f32_16x16x32_bf16(pa[g][1], ones, l_acc[g], 0, 0, 0);
    }
    #pragma unroll
    for (int dc = 0; dc < 4; ++dc) {
      bf16x8 vb0 = *(const bf16x8*)&v_lds[dc * 16 + l15][quad * 8];
      bf16x8 vb1 = *(const bf16x8*)&v_lds[dc * 16 + l15][32 + quad * 8];
      #pragma unroll
      for (int g = 0; g < 2; ++g) {
        o_acc[g][dc] = __builtin_amdgcn_mfma_f32_16x16x32_bf16(pa[g][0], vb0, o_acc[g][dc], 0, 0, 0);
        o_acc[g][dc] = __builtin_amdgcn_mfma_f32_16x16x32_bf16(pa[g][1], vb1, o_acc[g][dc], 0, 0, 0);
      }
    }
  }

  #pragma unroll
  for (int g = 0; g < 2; ++g) {
    float inv_l[4];
    #pragma unroll
    for (int r = 0; r < 4; ++r) inv_l[r] = 1.f / l_acc[g][r];
    #pragma unroll
    for (int dc = 0; dc < 4; ++dc) {
      #pragma unroll
      for (int r = 0; r < 4; ++r) {
        int s = s0w + g * 16 + quad * 4 + r;
        size_t idx = ((size_t)b * S_ + s) * C_ + n * 64 + dc * 16 + l15;
        hflat_bf[idx] = f2bf_fast(o_acc[g][dc][r] * inv_l[r]);
      }
    }
  }
}

// ---------------- INL step (64x64 tile, 1024 blocks = 4/CU): bf16 h chain ----------------
__global__ __launch_bounds__(256) void inl_step_mfma(
    const unsigned short* __restrict__ hbf_in, const unsigned short* __restrict__ Wbf,
    const float* __restrict__ bias, unsigned short* __restrict__ hbf_out) {
  __shared__ __align__(16) unsigned short ldsA[64 * 32];
  __shared__ __align__(16) unsigned short ldsB[64 * 32];
  int bm = blockIdx.y * 64, bn = blockIdx.x * 64;
  f32x4 acc[4];
  #pragma unroll
  for (int t = 0; t < 4; ++t) acc[t] = (f32x4){0.f, 0.f, 0.f, 0.f};
  gemm_nt_core<64, 64, 2, 2>(hbf_in + (size_t)bm * 512,
                             Wbf + (size_t)bn * 512, ldsA, ldsB, acc);
  int tid = threadIdx.x, w = tid >> 6, lane = tid & 63, quad = lane >> 4, l15 = lane & 15;
  int wm = w >> 1, wn = w & 1;
  #pragma unroll
  for (int i = 0; i < 2; ++i) {
    #pragma unroll
    for (int j = 0; j < 2; ++j) {
      int m0 = bm + wm * 32 + i * 16 + quad * 4;
      int o = bn + wn * 32 + j * 16 + l15;
      float bv = bias[o];
      f32x4 v = acc[i * 2 + j];
      #pragma unroll
      for (int r = 0; r < 4; ++r) {
        size_t idx = (size_t)(m0 + r) * 512 + o;
        float hin = bf2f(hbf_in[idx]);
        hbf_out[idx] = f2bf_fast(hin + DT_STEP * fast_tanh(v[r] + bv));
      }
    }
  }
}

// ---------------- Proj (64x64 tile, 1024 blocks) + residual ----------------
__global__ __launch_bounds__(256) void gemm_proj_mfma(
    const unsigned short* __restrict__ Wbf, const unsigned short* __restrict__ hbf,
    const float* __restrict__ pb, const float* __restrict__ x,
    float* __restrict__ Out) {
  __shared__ __align__(16) unsigned short ldsA[64 * 32];
  __shared__ __align__(16) unsigned short ldsB[64 * 32];
  int bm = blockIdx.y * 64, bn = blockIdx.x * 64;
  f32x4 acc[4];
  #pragma unroll
  for (int t = 0; t < 4; ++t) acc[t] = (f32x4){0.f, 0.f, 0.f, 0.f};
  gemm_nt_core<64, 64, 2, 2>(Wbf + (size_t)bm * 512,
                             hbf + (size_t)bn * 512, ldsA, ldsB, acc);
  int tid = threadIdx.x, w = tid >> 6, lane = tid & 63, quad = lane >> 4, l15 = lane & 15;
  int wm = w >> 1, wn = w & 1;
  #pragma unroll
  for (int i = 0; i < 2; ++i) {
    #pragma unroll
    for (int j = 0; j < 2; ++j) {
      int o0 = bm + wm * 32 + i * 16 + quad * 4;
      int ng = bn + wn * 32 + j * 16 + l15;
      int b = ng >> 10, s = ng & 1023;
      f32x4 v = acc[i * 2 + j];
      #pragma unroll
      for (int r = 0; r < 4; ++r) {
        size_t idx = ((size_t)b * C_ + o0 + r) * S_ + s;
        Out[idx] = x[idx] + pb[o0 + r] + v[r];
      }
    }
  }
}

extern "C" void kernel_launch(void* const* d_in, const int* in_sizes, int n_in,
                              void* d_out, int out_size, void* d_ws, size_t ws_size,
                              hipStream_t stream) {
  const float* x        = (const float*)d_in[0];
  const float* gn_scale = (const float*)d_in[1];
  const float* gn_bias  = (const float*)d_in[2];
  const float* qkv_w    = (const float*)d_in[3];
  const float* qkv_b    = (const float*)d_in[4];
  const float* proj_w   = (const float*)d_in[5];
  const float* proj_b   = (const float*)d_in[6];
  const float* inl_w    = (const float*)d_in[7];
  const float* inl_b    = (const float*)d_in[8];
  float* out = (float*)d_out;
  float* ws = (float*)d_ws;

  unsigned short* Qt  = (unsigned short*)(ws + 8388608);
  unsigned short* Kt  = (unsigned short*)(ws + 10485760);
  unsigned short* Vt  = (unsigned short*)(ws + 12582912);
  unsigned short* h_t = (unsigned short*)(ws + 14680064);
  unsigned short* Bbf = h_t;
  unsigned short* Abf = (unsigned short*)(ws + 16777216);
  float* gpart = ws + 18874368;
  unsigned short* qkvw_bf  = (unsigned short*)(ws + 18878464);
  unsigned short* inlw_bf  = qkvw_bf + 786432;
  unsigned short* projw_bf = inlw_bf + 262144;

  prep_kernel<<<1152, 256, 0, stream>>>(qkv_w, inl_w, proj_w, qkvw_bf, inlw_bf, projw_bf, x, gpart);
  gn_apply_t<<<1024, 256, 0, stream>>>(x, gpart, gn_scale, gn_bias, h_t);
  gemm_qkv_mfma<<<dim3(8, 12, 8), 256, 0, stream>>>(qkvw_bf, h_t, qkv_b, Qt, Kt, Vt);
  attn_mfma<<<512, 256, 0, stream>>>(Qt, Kt, Vt, Abf);
  inl_step_mfma<<<dim3(8, 128), 256, 0, stream>>>(Abf, inlw_bf, inl_b, Bbf);
  inl_step_mfma<<<dim3(8, 128), 256, 0, stream>>>(Bbf, inlw_bf, inl_b, Abf);
  inl_step_mfma<<<dim3(8, 128), 256, 0, stream>>>(Abf, inlw_bf, inl_b, Bbf);
  gemm_proj_mfma<<<dim3(128, 8), 256, 0, stream>>>(projw_bf, Bbf, proj_b, x, out);
}

// Round 13
// 205.939 us; speedup vs baseline: 1.1137x; 1.0145x over previous
//
#include <hip/hip_runtime.h>
#include <math.h>

#define B_ 8
#define C_ 512
#define S_ 1024
#define HD 64
#define NHEADS 8
#define NGROUPS 8
#define DT_STEP 0.1f
#define EPS_GN 1e-5f
#define LOG2E 1.4426950408889634f

typedef __attribute__((ext_vector_type(8))) short bf16x8;
typedef __attribute__((ext_vector_type(4))) float f32x4;
typedef __attribute__((ext_vector_type(8))) unsigned short ushort8;
typedef __attribute__((ext_vector_type(4))) unsigned short ushort4_t;

static __device__ __forceinline__ unsigned short f2bf(float f) {     // RNE (cold paths)
  unsigned int u = __builtin_bit_cast(unsigned int, f);
  u += 0x7fff + ((u >> 16) & 1);
  return (unsigned short)(u >> 16);
}

static __device__ __forceinline__ unsigned short f2bf_fast(float f) { // round-half-up (hot paths)
  unsigned int u = __builtin_bit_cast(unsigned int, f);
  return (unsigned short)((u + 0x8000u) >> 16);
}

static __device__ __forceinline__ float bf2f(unsigned short u) {
  unsigned int t = ((unsigned int)u) << 16;
  return __builtin_bit_cast(float, t);
}

static __device__ __forceinline__ float exp2_raw(float x) {
  return __builtin_amdgcn_exp2f(x);    // single v_exp_f32
}

static __device__ __forceinline__ float fast_tanh(float x) {
  float xc = fminf(fmaxf(x, -15.f), 15.f);
  float e = exp2_raw(xc * (2.0f * LOG2E));
  return (e - 1.f) / (e + 1.f);
}

// ---------------- prep: cast fp32 weights -> bf16  +  GroupNorm partial sums ----------------
__global__ __launch_bounds__(256) void prep_kernel(
    const float* __restrict__ a, const float* __restrict__ b, const float* __restrict__ c,
    unsigned short* __restrict__ A, unsigned short* __restrict__ B, unsigned short* __restrict__ C,
    const float* __restrict__ x, float* __restrict__ gpart) {
  int bid = blockIdx.x;
  int tid = threadIdx.x;
  if (bid < 640) {
    const float* src; unsigned short* dst; int off;
    if (bid < 384) { src = a; dst = A; off = bid * 2048; }
    else if (bid < 512) { src = b; dst = B; off = (bid - 384) * 2048; }
    else { src = c; dst = C; off = (bid - 512) * 2048; }
    int i = off + tid * 8;
    f32x4 v0 = *(const f32x4*)(src + i);
    f32x4 v1 = *(const f32x4*)(src + i + 4);
    ushort8 o;
    o[0] = f2bf(v0[0]); o[1] = f2bf(v0[1]); o[2] = f2bf(v0[2]); o[3] = f2bf(v0[3]);
    o[4] = f2bf(v1[0]); o[5] = f2bf(v1[1]); o[6] = f2bf(v1[2]); o[7] = f2bf(v1[3]);
    *(ushort8*)(dst + i) = o;
    return;
  }
  int sbid = bid - 640;
  int bg = sbid >> 3, chunk = sbid & 7;
  const float* xp = x + (size_t)bg * 65536 + (size_t)chunk * 8192;
  float sum = 0.f, sq = 0.f;
  #pragma unroll
  for (int i = 0; i < 8; ++i) {
    f32x4 v = *(const f32x4*)(xp + i * 1024 + tid * 4);
    sum += v[0] + v[1] + v[2] + v[3];
    sq += v[0]*v[0] + v[1]*v[1] + v[2]*v[2] + v[3]*v[3];
  }
  #pragma unroll
  for (int off = 32; off >= 1; off >>= 1) {
    sum += __shfl_xor(sum, off, 64);
    sq  += __shfl_xor(sq, off, 64);
  }
  __shared__ float s1[4], s2[4];
  int wave = tid >> 6, lane = tid & 63;
  if (lane == 0) { s1[wave] = sum; s2[wave] = sq; }
  __syncthreads();
  if (tid == 0) {
    float S = s1[0] + s1[1] + s1[2] + s1[3];
    float Q = s2[0] + s2[1] + s2[2] + s2[3];
    gpart[bg * 16 + chunk * 2] = S;
    gpart[bg * 16 + chunk * 2 + 1] = Q;
  }
}

// ---------------- GroupNorm pass 2: normalize + transpose to h_t[B,S,C] bf16 ----------------
__global__ __launch_bounds__(256) void gn_apply_t(
    const float* __restrict__ x, const float* __restrict__ gpart,
    const float* __restrict__ scale, const float* __restrict__ bias,
    unsigned short* __restrict__ h_t) {
  int bid = blockIdx.x;
  int bg = bid >> 4, st = bid & 15;
  int b = bg >> 3, g = bg & 7;
  float S = 0.f, Q = 0.f;
  #pragma unroll
  for (int i = 0; i < 8; ++i) {
    S += gpart[bg * 16 + i * 2];
    Q += gpart[bg * 16 + i * 2 + 1];
  }
  float mean = S / 65536.f;
  float var = Q / 65536.f - mean * mean;
  float inv = rsqrtf(var + EPS_GN);

  int tid = threadIdx.x;
  int sl = tid >> 2;
  int cq = (tid & 3) * 16;
  float sA[16], sB[16];
  #pragma unroll
  for (int u = 0; u < 16; ++u) {
    float scv = scale[g * 64 + cq + u];
    sA[u] = inv * scv;
    sB[u] = bias[g * 64 + cq + u] - mean * inv * scv;
  }

  const float* xp = x + ((size_t)b * C_ + (size_t)g * 64) * S_;
  __shared__ float tile[64][65];
  #pragma unroll
  for (int it = 0; it < 16; ++it) {
    int lin = it * 256 + tid;
    int c = lin >> 6, s = lin & 63;
    tile[c][s] = xp[(size_t)c * S_ + st * 64 + s];
  }
  __syncthreads();
  unsigned short vals[16];
  #pragma unroll
  for (int u = 0; u < 16; ++u)
    vals[u] = f2bf_fast(tile[cq + u][sl] * sA[u] + sB[u]);
  unsigned short* dst = h_t + ((size_t)b * S_ + st * 64 + sl) * C_ + g * 64 + cq;
  ushort8 lo, hi;
  #pragma unroll
  for (int u = 0; u < 8; ++u) { lo[u] = vals[u]; hi[u] = vals[u + 8]; }
  *(ushort8*)dst = lo;
  *(ushort8*)(dst + 8) = hi;
}

// ---------------- NT GEMM core, register-prefetch pipelined staging ----------------
// C[MB,NB] = A[MB,512] * B[NB,512]^T ; next k-slab loads issue during MFMA phase.
template<int MB, int NB, int WMG, int WNG>
__device__ __forceinline__ void gemm_nt_core(
    const unsigned short* __restrict__ Ab,
    const unsigned short* __restrict__ Bb,
    unsigned short* ldsA, unsigned short* ldsB,
    f32x4* acc) {
  constexpr int TI = (MB / WMG) / 16;
  constexpr int TJ = (NB / WNG) / 16;
  constexpr int NQA = MB * 4 / 256;          // 16B chunks per thread (A)
  constexpr int NQB = NB * 4 / 256;
  const int K = 512;
  const int tid = threadIdx.x;
  const int w = tid >> 6, lane = tid & 63, quad = lane >> 4, l15 = lane & 15;
  const int wm = (WNG == 1) ? w : ((WMG == 1) ? 0 : (w >> 1));
  const int wn = (WNG == 1) ? 0 : ((WMG == 1) ? w : (w & 1));

  ushort8 apf[NQA], bpf[NQB];
  #pragma unroll
  for (int q = 0; q < NQA; ++q) {
    int c = q * 256 + tid;
    apf[q] = *(const ushort8*)(Ab + (size_t)(c >> 2) * K + (c & 3) * 8);
  }
  #pragma unroll
  for (int q = 0; q < NQB; ++q) {
    int c = q * 256 + tid;
    bpf[q] = *(const ushort8*)(Bb + (size_t)(c >> 2) * K + (c & 3) * 8);
  }

  for (int k0 = 0; k0 < K; k0 += 32) {
    __syncthreads();                         // prior slab consumed
    #pragma unroll
    for (int q = 0; q < NQA; ++q) {
      int c = q * 256 + tid;
      *(ushort8*)(ldsA + c * 8) = apf[q];
    }
    #pragma unroll
    for (int q = 0; q < NQB; ++q) {
      int c = q * 256 + tid;
      *(ushort8*)(ldsB + c * 8) = bpf[q];
    }
    __syncthreads();
    if (k0 + 32 < K) {                       // issue next-slab loads; waited next iter
      #pragma unroll
      for (int q = 0; q < NQA; ++q) {
        int c = q * 256 + tid;
        apf[q] = *(const ushort8*)(Ab + (size_t)(c >> 2) * K + k0 + 32 + (c & 3) * 8);
      }
      #pragma unroll
      for (int q = 0; q < NQB; ++q) {
        int c = q * 256 + tid;
        bpf[q] = *(const ushort8*)(Bb + (size_t)(c >> 2) * K + k0 + 32 + (c & 3) * 8);
      }
    }
    bf16x8 af[TI], bfr[TJ];
    #pragma unroll
    for (int i = 0; i < TI; ++i)
      af[i] = *(const bf16x8*)(ldsA + (wm * (MB / WMG) + i * 16 + l15) * 32 + quad * 8);
    #pragma unroll
    for (int j = 0; j < TJ; ++j)
      bfr[j] = *(const bf16x8*)(ldsB + (wn * (NB / WNG) + j * 16 + l15) * 32 + quad * 8);
    #pragma unroll
    for (int i = 0; i < TI; ++i)
      #pragma unroll
      for (int j = 0; j < TJ; ++j)
        acc[i * TJ + j] = __builtin_amdgcn_mfma_f32_16x16x32_bf16(af[i], bfr[j], acc[i * TJ + j], 0, 0, 0);
  }
}

// ---------------- QKV GEMM: W_bf[1536,512] x h_t[b][1024,512]^T ----------------
__global__ __launch_bounds__(256) void gemm_qkv_mfma(
    const unsigned short* __restrict__ Wbf, const unsigned short* __restrict__ h_t,
    const float* __restrict__ bias,
    unsigned short* __restrict__ Qt, unsigned short* __restrict__ Kt,
    unsigned short* __restrict__ Vt) {
  __shared__ __align__(16) unsigned short ldsA[128 * 32];
  __shared__ __align__(16) unsigned short ldsB[128 * 32];
  int b = blockIdx.z;
  int bm = blockIdx.y * 128, bn = blockIdx.x * 128;
  f32x4 acc[16];
  #pragma unroll
  for (int t = 0; t < 16; ++t) acc[t] = (f32x4){0.f, 0.f, 0.f, 0.f};
  gemm_nt_core<128, 128, 2, 2>(Wbf + (size_t)bm * 512,
                               h_t + ((size_t)b * S_ + bn) * 512, ldsA, ldsB, acc);
  int tid = threadIdx.x, w = tid >> 6, lane = tid & 63, quad = lane >> 4, l15 = lane & 15;
  int wm = w >> 1, wn = w & 1;
  int tensor = bm >> 9;
  float qscale = (tensor == 0) ? 0.125f * LOG2E : 1.0f;
  #pragma unroll
  for (int i = 0; i < 4; ++i) {
    #pragma unroll
    for (int j = 0; j < 4; ++j) {
      int m0 = bm + wm * 64 + i * 16 + quad * 4;
      int ng = bn + wn * 64 + j * 16 + l15;
      f32x4 v = acc[i * 4 + j];
      if (tensor < 2) {
        int head = (m0 >> 6) & 7, d0 = m0 & 63;
        ushort4_t pk;
        #pragma unroll
        for (int r = 0; r < 4; ++r) pk[r] = f2bf((v[r] + bias[m0 + r]) * qscale);
        unsigned short* dst = (tensor ? Kt : Qt) +
            (((size_t)(b * 8 + head) * S_ + ng) * 64 + d0);
        *(ushort4_t*)dst = pk;
      } else {
        #pragma unroll
        for (int r = 0; r < 4; ++r)
          Vt[(size_t)b * (C_ * S_) + (size_t)(m0 - 1024 + r) * S_ + ng] = f2bf(v[r] + bias[m0 + r]);
      }
    }
  }
}

// ---------------- Flash attention: transposed scores, 2 q-groups/wave, reg-prefetched K/V ----------------
// grid 512: bid = sblk*64 + (b*8+n); 4 waves x 32 q-rows (2 groups of 16)
__global__ __launch_bounds__(256) void attn_mfma(
    const unsigned short* __restrict__ Qt,   // [B][NH][S][HD] (pre-scaled, incl log2e)
    const unsigned short* __restrict__ Kt,
    const unsigned short* __restrict__ Vt,   // [B][C][S]
    unsigned short* __restrict__ hflat_bf) { // [B][S][C] bf16
  int tid = threadIdx.x, wave = tid >> 6, lane = tid & 63;
  int quad = lane >> 4, l15 = lane & 15;
  int bid = blockIdx.x;
  int bn = bid & 63, sblk = bid >> 6, b = bn >> 3, n = bn & 7;
  int s0w = sblk * 128 + wave * 32;

  __shared__ unsigned short k_lds[64][72];
  __shared__ unsigned short v_lds[64][72];
  __shared__ unsigned short p_lds[4][2][16][72];  // [wave][group][s][t], A-layout

  const unsigned short* Kb = Kt + ((size_t)(b * 8 + n)) * S_ * 64;
  const unsigned short* Vb = Vt + ((size_t)b * C_ + n * 64) * S_;

  bf16x8 qa[2][2];
  #pragma unroll
  for (int g = 0; g < 2; ++g) {
    const unsigned short* Qb = Qt + (((size_t)(b * 8 + n)) * S_ + s0w + g * 16 + l15) * 64;
    qa[g][0] = *(const bf16x8*)(Qb + quad * 8);
    qa[g][1] = *(const bf16x8*)(Qb + 32 + quad * 8);
  }

  bf16x8 ones;
  #pragma unroll
  for (int j = 0; j < 8; ++j) ones[j] = (short)0x3F80;

  f32x4 o_acc[2][4];
  f32x4 l_acc[2];
  #pragma unroll
  for (int g = 0; g < 2; ++g) {
    l_acc[g] = (f32x4){0.f, 0.f, 0.f, 0.f};
    #pragma unroll
    for (int dc = 0; dc < 4; ++dc) o_acc[g][dc] = (f32x4){0.f, 0.f, 0.f, 0.f};
  }

  int row0 = tid >> 3, c80 = (tid & 7) * 8;
  int row1 = (tid + 256) >> 3, c81 = c80;

  ushort8 kreg[2], vreg[2];
  kreg[0] = *(const ushort8*)(Kb + (size_t)row0 * 64 + c80);
  kreg[1] = *(const ushort8*)(Kb + (size_t)row1 * 64 + c81);
  vreg[0] = *(const ushort8*)(Vb + (size_t)row0 * S_ + c80);
  vreg[1] = *(const ushort8*)(Vb + (size_t)row1 * S_ + c81);

  for (int t0 = 0; t0 < S_; t0 += 64) {
    __syncthreads();
    *(ushort8*)&k_lds[row0][c80] = kreg[0];
    *(ushort8*)&k_lds[row1][c81] = kreg[1];
    *(ushort8*)&v_lds[row0][c80] = vreg[0];
    *(ushort8*)&v_lds[row1][c81] = vreg[1];
    __syncthreads();
    if (t0 + 64 < S_) {
      int t1 = t0 + 64;
      kreg[0] = *(const ushort8*)(Kb + (size_t)(t1 + row0) * 64 + c80);
      kreg[1] = *(const ushort8*)(Kb + (size_t)(t1 + row1) * 64 + c81);
      vreg[0] = *(const ushort8*)(Vb + (size_t)row0 * S_ + t1 + c80);
      vreg[1] = *(const ushort8*)(Vb + (size_t)row1 * S_ + t1 + c81);
    }

    // Transposed scores: St[t][s] = sum_d K[t][d] Q[s][d]
    f32x4 sc[2][4];
    #pragma unroll
    for (int tc = 0; tc < 4; ++tc) {
      bf16x8 kb0 = *(const bf16x8*)&k_lds[tc * 16 + l15][quad * 8];
      bf16x8 kb1 = *(const bf16x8*)&k_lds[tc * 16 + l15][32 + quad * 8];
      #pragma unroll
      for (int g = 0; g < 2; ++g) {
        f32x4 c = {0.f, 0.f, 0.f, 0.f};
        c = __builtin_amdgcn_mfma_f32_16x16x32_bf16(kb0, qa[g][0], c, 0, 0, 0);
        sc[g][tc] = __builtin_amdgcn_mfma_f32_16x16x32_bf16(kb1, qa[g][1], c, 0, 0, 0);
      }
    }

    // exp -> P[s][t] in LDS via contiguous b64 writes
    #pragma unroll
    for (int g = 0; g < 2; ++g)
      #pragma unroll
      for (int tc = 0; tc < 4; ++tc) {
        ushort4_t p4;
        #pragma unroll
        for (int r = 0; r < 4; ++r) p4[r] = f2bf_fast(exp2_raw(sc[g][tc][r]));
        *(ushort4_t*)&p_lds[wave][g][l15][tc * 16 + quad * 4] = p4;
      }

    bf16x8 pa[2][2];
    #pragma unroll
    for (int g = 0; g < 2; ++g) {
      pa[g][0] = *(const bf16x8*)&p_lds[wave][g][l15][quad * 8];
      pa[g][1] = *(const bf16x8*)&p_lds[wave][g][l15][32 + quad * 8];
      l_acc[g] = __builtin_amdgcn_mfma_f32_16x16x32_bf16(pa[g][0], ones, l_acc[g], 0, 0, 0);
      l_acc[g] = __builtin_amdgcn_mfma_f32_16x16x32_bf16(pa[g][1], ones, l_acc[g], 0, 0, 0);
    }
    #pragma unroll
    for (int dc = 0; dc < 4; ++dc) {
      bf16x8 vb0 = *(const bf16x8*)&v_lds[dc * 16 + l15][quad * 8];
      bf16x8 vb1 = *(const bf16x8*)&v_lds[dc * 16 + l15][32 + quad * 8];
      #pragma unroll
      for (int g = 0; g < 2; ++g) {
        o_acc[g][dc] = __builtin_amdgcn_mfma_f32_16x16x32_bf16(pa[g][0], vb0, o_acc[g][dc], 0, 0, 0);
        o_acc[g][dc] = __builtin_amdgcn_mfma_f32_16x16x32_bf16(pa[g][1], vb1, o_acc[g][dc], 0, 0, 0);
      }
    }
  }

  #pragma unroll
  for (int g = 0; g < 2; ++g) {
    float inv_l[4];
    #pragma unroll
    for (int r = 0; r < 4; ++r) inv_l[r] = 1.f / l_acc[g][r];
    #pragma unroll
    for (int dc = 0; dc < 4; ++dc) {
      #pragma unroll
      for (int r = 0; r < 4; ++r) {
        int s = s0w + g * 16 + quad * 4 + r;
        size_t idx = ((size_t)b * S_ + s) * C_ + n * 64 + dc * 16 + l15;
        hflat_bf[idx] = f2bf_fast(o_acc[g][dc][r] * inv_l[r]);
      }
    }
  }
}

// ---------------- INL step (64x64 tile, 1024 blocks = 4/CU): bf16 h chain ----------------
__global__ __launch_bounds__(256) void inl_step_mfma(
    const unsigned short* __restrict__ hbf_in, const unsigned short* __restrict__ Wbf,
    const float* __restrict__ bias, unsigned short* __restrict__ hbf_out) {
  __shared__ __align__(16) unsigned short ldsA[64 * 32];
  __shared__ __align__(16) unsigned short ldsB[64 * 32];
  int bm = blockIdx.y * 64, bn = blockIdx.x * 64;
  f32x4 acc[4];
  #pragma unroll
  for (int t = 0; t < 4; ++t) acc[t] = (f32x4){0.f, 0.f, 0.f, 0.f};
  gemm_nt_core<64, 64, 2, 2>(hbf_in + (size_t)bm * 512,
                             Wbf + (size_t)bn * 512, ldsA, ldsB, acc);
  int tid = threadIdx.x, w = tid >> 6, lane = tid & 63, quad = lane >> 4, l15 = lane & 15;
  int wm = w >> 1, wn = w & 1;
  #pragma unroll
  for (int i = 0; i < 2; ++i) {
    #pragma unroll
    for (int j = 0; j < 2; ++j) {
      int m0 = bm + wm * 32 + i * 16 + quad * 4;
      int o = bn + wn * 32 + j * 16 + l15;
      float bv = bias[o];
      f32x4 v = acc[i * 2 + j];
      #pragma unroll
      for (int r = 0; r < 4; ++r) {
        size_t idx = (size_t)(m0 + r) * 512 + o;
        float hin = bf2f(hbf_in[idx]);
        hbf_out[idx] = f2bf_fast(hin + DT_STEP * fast_tanh(v[r] + bv));
      }
    }
  }
}

// ---------------- Proj (64x64 tile, 1024 blocks) + residual ----------------
__global__ __launch_bounds__(256) void gemm_proj_mfma(
    const unsigned short* __restrict__ Wbf, const unsigned short* __restrict__ hbf,
    const float* __restrict__ pb, const float* __restrict__ x,
    float* __restrict__ Out) {
  __shared__ __align__(16) unsigned short ldsA[64 * 32];
  __shared__ __align__(16) unsigned short ldsB[64 * 32];
  int bm = blockIdx.y * 64, bn = blockIdx.x * 64;
  f32x4 acc[4];
  #pragma unroll
  for (int t = 0; t < 4; ++t) acc[t] = (f32x4){0.f, 0.f, 0.f, 0.f};
  gemm_nt_core<64, 64, 2, 2>(Wbf + (size_t)bm * 512,
                             hbf + (size_t)bn * 512, ldsA, ldsB, acc);
  int tid = threadIdx.x, w = tid >> 6, lane = tid & 63, quad = lane >> 4, l15 = lane & 15;
  int wm = w >> 1, wn = w & 1;
  #pragma unroll
  for (int i = 0; i < 2; ++i) {
    #pragma unroll
    for (int j = 0; j < 2; ++j) {
      int o0 = bm + wm * 32 + i * 16 + quad * 4;
      int ng = bn + wn * 32 + j * 16 + l15;
      int b = ng >> 10, s = ng & 1023;
      f32x4 v = acc[i * 2 + j];
      #pragma unroll
      for (int r = 0; r < 4; ++r) {
        size_t idx = ((size_t)b * C_ + o0 + r) * S_ + s;
        Out[idx] = x[idx] + pb[o0 + r] + v[r];
      }
    }
  }
}

extern "C" void kernel_launch(void* const* d_in, const int* in_sizes, int n_in,
                              void* d_out, int out_size, void* d_ws, size_t ws_size,
                              hipStream_t stream) {
  const float* x        = (const float*)d_in[0];
  const float* gn_scale = (const float*)d_in[1];
  const float* gn_bias  = (const float*)d_in[2];
  const float* qkv_w    = (const float*)d_in[3];
  const float* qkv_b    = (const float*)d_in[4];
  const float* proj_w   = (const float*)d_in[5];
  const float* proj_b   = (const float*)d_in[6];
  const float* inl_w    = (const float*)d_in[7];
  const float* inl_b    = (const float*)d_in[8];
  float* out = (float*)d_out;
  float* ws = (float*)d_ws;

  unsigned short* Qt  = (unsigned short*)(ws + 8388608);
  unsigned short* Kt  = (unsigned short*)(ws + 10485760);
  unsigned short* Vt  = (unsigned short*)(ws + 12582912);
  unsigned short* h_t = (unsigned short*)(ws + 14680064);
  unsigned short* Bbf = h_t;
  unsigned short* Abf = (unsigned short*)(ws + 16777216);
  float* gpart = ws + 18874368;
  unsigned short* qkvw_bf  = (unsigned short*)(ws + 18878464);
  unsigned short* inlw_bf  = qkvw_bf + 786432;
  unsigned short* projw_bf = inlw_bf + 262144;

  prep_kernel<<<1152, 256, 0, stream>>>(qkv_w, inl_w, proj_w, qkvw_bf, inlw_bf, projw_bf, x, gpart);
  gn_apply_t<<<1024, 256, 0, stream>>>(x, gpart, gn_scale, gn_bias, h_t);
  gemm_qkv_mfma<<<dim3(8, 12, 8), 256, 0, stream>>>(qkvw_bf, h_t, qkv_b, Qt, Kt, Vt);
  attn_mfma<<<512, 256, 0, stream>>>(Qt, Kt, Vt, Abf);
  inl_step_mfma<<<dim3(8, 128), 256, 0, stream>>>(Abf, inlw_bf, inl_b, Bbf);
  inl_step_mfma<<<dim3(8, 128), 256, 0, stream>>>(Bbf, inlw_bf, inl_b, Abf);
  inl_step_mfma<<<dim3(8, 128), 256, 0, stream>>>(Abf, inlw_bf, inl_b, Bbf);
  gemm_proj_mfma<<<dim3(128, 8), 256, 0, stream>>>(projw_bf, Bbf, proj_b, x, out);
}